// Round 1
// baseline (5736.926 us; speedup 1.0000x reference)
//
#include <hip/hip_runtime.h>
#include <hip/hip_bf16.h>
#include <hip/hip_cooperative_groups.h>

namespace cg = cooperative_groups;

typedef __hip_bfloat16 bf16;
typedef __attribute__((ext_vector_type(8))) short bf16x8;
typedef __attribute__((ext_vector_type(4))) float f32x4;

#define T_STEPS 128
// B=64, I=256, H=512, E=4, G=2048(=4H), K2=E*H=2048, K1=E*I=1024

// ---------------- prep kernels ----------------

// W2T[o][e*512+hh] = Wh[e][o][hh]   (bf16, [2048][2048])
__global__ void prep_w2t(const float* __restrict__ Wh, bf16* __restrict__ W2T) {
    int idx = blockIdx.x * 256 + threadIdx.x;          // 2048*2048
    int o = idx >> 11, k = idx & 2047;
    int e = k >> 9, hh = k & 511;
    W2T[idx] = __float2bfloat16(Wh[((size_t)((e << 11) + o) << 9) + hh]);
}

// W1T[o][e*256+i] = Wi[e][o][i]     (bf16, [2048][1024])
__global__ void prep_w1t(const float* __restrict__ Wi, bf16* __restrict__ W1T) {
    int idx = blockIdx.x * 256 + threadIdx.x;          // 2048*1024
    int o = idx >> 10, k = idx & 1023;
    int e = k >> 8, i = k & 255;
    W1T[idx] = __float2bfloat16(Wi[((size_t)((e << 11) + o) << 8) + i]);
}

// A1[t*64+b][e*256+i] = coef[b][e] * x[t][b][i]   (bf16, [8192][1024])
__global__ void prep_a1(const float* __restrict__ x, const float* __restrict__ coef,
                        bf16* __restrict__ A1) {
    int idx = blockIdx.x * 256 + threadIdx.x;          // 8192*1024
    int row = idx >> 10, k = idx & 1023;
    int b = row & 63;
    int e = k >> 8, i = k & 255;
    A1[idx] = __float2bfloat16(coef[(b << 2) + e] * x[((size_t)row << 8) + i]);
}

// biasmix[b][o] = sum_e coef[b][e]*(bi[e][o]+bh[e][o])   (f32, [64][2048])
__global__ void prep_bias(const float* __restrict__ coef, const float* __restrict__ bi,
                          const float* __restrict__ bh, float* __restrict__ biasmix) {
    int idx = blockIdx.x * 256 + threadIdx.x;          // 64*2048
    int b = idx >> 11, o = idx & 2047;
    float s = 0.f;
#pragma unroll
    for (int e = 0; e < 4; ++e)
        s += coef[(b << 2) + e] * (bi[(e << 11) + o] + bh[(e << 11) + o]);
    biasmix[idx] = s;
}

// z0[b][e*512+j] = coef[b][e]*h0[b][j]   (bf16, ping-pong buffer 0)
__global__ void prep_z0(const float* __restrict__ h0, const float* __restrict__ coef,
                        bf16* __restrict__ z) {
    int idx = blockIdx.x * 256 + threadIdx.x;          // 64*2048
    int b = idx >> 11, k = idx & 2047;
    int e = k >> 9, j = k & 511;
    z[idx] = __float2bfloat16(coef[(b << 2) + e] * h0[(b << 9) + j]);
}

// ---------------- main recurrent kernel (cooperative) ----------------
// 128 WGs x 256 threads. WG wg owns hidden units j0=4*wg .. j0+3, i.e. the 16
// gate columns o = q*512 + j0 + jj (q=gate 0..3, jj=0..3). Weight slices live
// in LDS across all 128 steps; c-state lives in registers.

__launch_bounds__(256, 1)
__global__ void lstm_rec(const bf16* __restrict__ W2T, const bf16* __restrict__ W1T,
                         const bf16* __restrict__ A1, const float* __restrict__ biasmix,
                         bf16* z, const float* __restrict__ coef,
                         const float* __restrict__ c0, float* __restrict__ out) {
    constexpr int SP2 = 2048 + 8;   // pad: stride bytes 4112 -> banks spread
    constexpr int SP1 = 1024 + 8;
    __shared__ bf16  Wsl [16][SP2];   // [col n][k]  (B operand, K-major rows)
    __shared__ bf16  W1sl[16][SP1];
    __shared__ float g_lds [64][17];
    __shared__ float bias_l[64][17];

    const int wg  = blockIdx.x;       // 0..127
    const int j0  = wg << 2;
    const int tid = threadIdx.x;
    const int lane = tid & 63;
    const int wv  = tid >> 6;         // wave 0..3 -> rows 16*wv..+15

    // ---- load weight slices into LDS (once) ----
#pragma unroll 1
    for (int n = 0; n < 16; ++n) {
        int o = ((n >> 2) << 9) + j0 + (n & 3);
        const bf16* s2 = W2T + ((size_t)o << 11);
        for (int k = tid; k < 2048; k += 256) Wsl[n][k] = s2[k];
        const bf16* s1 = W1T + ((size_t)o << 10);
        for (int k = tid; k < 1024; k += 256) W1sl[n][k] = s1[k];
    }
    for (int idx = tid; idx < 64 * 16; idx += 256) {
        int b = idx >> 4, n = idx & 15;
        int o = ((n >> 2) << 9) + j0 + (n & 3);
        bias_l[b][n] = biasmix[(b << 11) + o];
    }

    // ---- per-thread gate-phase state: tid -> (b_g, jj) ----
    const int b_g = tid >> 2, jj = tid & 3;
    float c_reg = c0[(b_g << 9) + j0 + jj];
    const float cf0 = coef[(b_g << 2) + 0];
    const float cf1 = coef[(b_g << 2) + 1];
    const float cf2 = coef[(b_g << 2) + 2];
    const float cf3 = coef[(b_g << 2) + 3];

    // MFMA lane mapping (16x16x32): A row = lane&15, k-group = lane>>4 (8 contig k)
    const int rlo  = lane & 15;
    const int kg   = lane >> 4;
    const int arow = (wv << 4) + rlo;   // sample index this lane loads for A

    __syncthreads();
    cg::grid_group gg = cg::this_grid();

    for (int t = 0; t < T_STEPS; ++t) {
        const bf16* zin  = z + ((size_t)(t & 1) << 17);    // 64*2048 elems/buf
        bf16*       zout = z + ((size_t)((t + 1) & 1) << 17);

        f32x4 acc0 = {0.f, 0.f, 0.f, 0.f};
        f32x4 acc1 = acc0, acc2 = acc0, acc3 = acc0;

        const bf16* za = zin + ((size_t)arow << 11) + (kg << 3);
        const bf16* xa = A1 + ((size_t)((t << 6) + arow) << 10) + (kg << 3);

        // hidden part: K = 2048 -> 64 MFMA k-steps, 4-way accumulator rotation
#pragma unroll
        for (int kk = 0; kk < 64; kk += 4) {
            bf16x8 a0 = *(const bf16x8*)(za + (kk + 0) * 32);
            bf16x8 a1 = *(const bf16x8*)(za + (kk + 1) * 32);
            bf16x8 a2 = *(const bf16x8*)(za + (kk + 2) * 32);
            bf16x8 a3 = *(const bf16x8*)(za + (kk + 3) * 32);
            bf16x8 b0 = *(const bf16x8*)(&Wsl[rlo][(kk + 0) * 32 + (kg << 3)]);
            bf16x8 b1 = *(const bf16x8*)(&Wsl[rlo][(kk + 1) * 32 + (kg << 3)]);
            bf16x8 b2 = *(const bf16x8*)(&Wsl[rlo][(kk + 2) * 32 + (kg << 3)]);
            bf16x8 b3 = *(const bf16x8*)(&Wsl[rlo][(kk + 3) * 32 + (kg << 3)]);
            acc0 = __builtin_amdgcn_mfma_f32_16x16x32_bf16(a0, b0, acc0, 0, 0, 0);
            acc1 = __builtin_amdgcn_mfma_f32_16x16x32_bf16(a1, b1, acc1, 0, 0, 0);
            acc2 = __builtin_amdgcn_mfma_f32_16x16x32_bf16(a2, b2, acc2, 0, 0, 0);
            acc3 = __builtin_amdgcn_mfma_f32_16x16x32_bf16(a3, b3, acc3, 0, 0, 0);
        }
        // input part: K = 1024 -> 32 MFMA k-steps
#pragma unroll
        for (int kk = 0; kk < 32; kk += 4) {
            bf16x8 a0 = *(const bf16x8*)(xa + (kk + 0) * 32);
            bf16x8 a1 = *(const bf16x8*)(xa + (kk + 1) * 32);
            bf16x8 a2 = *(const bf16x8*)(xa + (kk + 2) * 32);
            bf16x8 a3 = *(const bf16x8*)(xa + (kk + 3) * 32);
            bf16x8 b0 = *(const bf16x8*)(&W1sl[rlo][(kk + 0) * 32 + (kg << 3)]);
            bf16x8 b1 = *(const bf16x8*)(&W1sl[rlo][(kk + 1) * 32 + (kg << 3)]);
            bf16x8 b2 = *(const bf16x8*)(&W1sl[rlo][(kk + 2) * 32 + (kg << 3)]);
            bf16x8 b3 = *(const bf16x8*)(&W1sl[rlo][(kk + 3) * 32 + (kg << 3)]);
            acc0 = __builtin_amdgcn_mfma_f32_16x16x32_bf16(a0, b0, acc0, 0, 0, 0);
            acc1 = __builtin_amdgcn_mfma_f32_16x16x32_bf16(a1, b1, acc1, 0, 0, 0);
            acc2 = __builtin_amdgcn_mfma_f32_16x16x32_bf16(a2, b2, acc2, 0, 0, 0);
            acc3 = __builtin_amdgcn_mfma_f32_16x16x32_bf16(a3, b3, acc3, 0, 0, 0);
        }
        f32x4 g4 = (acc0 + acc1) + (acc2 + acc3);

        // C/D layout: col = lane&15, row = 4*(lane>>4) + r   (verified m89)
        const int brow = (wv << 4) + (kg << 2);
#pragma unroll
        for (int r = 0; r < 4; ++r)
            g_lds[brow + r][rlo] = g4[r] + bias_l[brow + r][rlo];
        __syncthreads();

        // ---- gate phase: thread (b_g, jj) ----
        float gi = g_lds[b_g][jj];
        float gf = g_lds[b_g][4 + jj];
        float gc = g_lds[b_g][8 + jj];
        float go = g_lds[b_g][12 + jj];
        float ig = 1.f / (1.f + __expf(-gi));
        float fg = 1.f / (1.f + __expf(-gf));
        float cc = tanhf(gc);
        float og = 1.f / (1.f + __expf(-go));
        float cn = fg * c_reg + ig * cc;
        float h  = og * tanhf(cn);
        c_reg = cn;

        out[((size_t)t << 15) + (b_g << 9) + j0 + jj] = h;
        const int zo = (b_g << 11) + j0 + jj;
        zout[zo       ] = __float2bfloat16(cf0 * h);
        zout[zo +  512] = __float2bfloat16(cf1 * h);
        zout[zo + 1024] = __float2bfloat16(cf2 * h);
        zout[zo + 1536] = __float2bfloat16(cf3 * h);
        if (t == T_STEPS - 1) {
            size_t base = (size_t)T_STEPS << 15;
            out[base + (b_g << 9) + j0 + jj] = h;
            out[base + (1 << 15) + (b_g << 9) + j0 + jj] = cn;
        }
        __threadfence();
        gg.sync();
    }
}

// ---------------- launch ----------------
extern "C" void kernel_launch(void* const* d_in, const int* in_sizes, int n_in,
                              void* d_out, int out_size, void* d_ws, size_t ws_size,
                              hipStream_t stream) {
    const float* x    = (const float*)d_in[0];
    const float* h0   = (const float*)d_in[1];
    const float* c0   = (const float*)d_in[2];
    const float* coef = (const float*)d_in[3];
    const float* Wi   = (const float*)d_in[4];
    const float* bi   = (const float*)d_in[5];
    const float* Wh   = (const float*)d_in[6];
    const float* bh   = (const float*)d_in[7];
    float* out = (float*)d_out;

    char* ws = (char*)d_ws;
    bf16*  W2T     = (bf16*)(ws);                                   // 8 MB
    bf16*  W1T     = (bf16*)(ws + (8u  << 20));                     // 4 MB
    bf16*  A1      = (bf16*)(ws + (12u << 20));                     // 16 MB
    float* biasmix = (float*)(ws + (28u << 20));                    // 512 KB
    bf16*  z       = (bf16*)(ws + (28u << 20) + (512u << 10));      // 512 KB (2 bufs)

    prep_w2t <<<16384, 256, 0, stream>>>(Wh, W2T);
    prep_w1t <<< 8192, 256, 0, stream>>>(Wi, W1T);
    prep_a1  <<<32768, 256, 0, stream>>>(x, coef, A1);
    prep_bias<<<  512, 256, 0, stream>>>(coef, bi, bh, biasmix);
    prep_z0  <<<  512, 256, 0, stream>>>(h0, coef, z);

    void* args[] = {(void*)&W2T, (void*)&W1T, (void*)&A1, (void*)&biasmix,
                    (void*)&z, (void*)&coef, (void*)&c0, (void*)&out};
    hipLaunchCooperativeKernel((void*)lstm_rec, dim3(128), dim3(256), args, 0, stream);
}

// Round 2
// 4449.457 us; speedup vs baseline: 1.2894x; 1.2894x over previous
//
#include <hip/hip_runtime.h>
#include <hip/hip_bf16.h>

typedef __hip_bfloat16 bf16;
typedef __attribute__((ext_vector_type(8))) short bf16x8;
typedef __attribute__((ext_vector_type(4))) float f32x4;

#define T_STEPS 128
#define NWG 128
// B=64, I=256, H=512, E=4, G=2048(=4H), K2=E*H=2048, K1=E*I=1024

// ---------------- prep kernels ----------------

// W2T[o][e*512+hh] = Wh[e][o][hh]   (bf16, [2048][2048])
__global__ void prep_w2t(const float* __restrict__ Wh, bf16* __restrict__ W2T) {
    int idx = blockIdx.x * 256 + threadIdx.x;          // 2048*2048
    int o = idx >> 11, k = idx & 2047;
    int e = k >> 9, hh = k & 511;
    W2T[idx] = __float2bfloat16(Wh[((size_t)((e << 11) + o) << 9) + hh]);
}

// W1T[o][e*256+i] = Wi[e][o][i]     (bf16, [2048][1024])
__global__ void prep_w1t(const float* __restrict__ Wi, bf16* __restrict__ W1T) {
    int idx = blockIdx.x * 256 + threadIdx.x;          // 2048*1024
    int o = idx >> 10, k = idx & 1023;
    int e = k >> 8, i = k & 255;
    W1T[idx] = __float2bfloat16(Wi[((size_t)((e << 11) + o) << 8) + i]);
}

// A1[t*64+b][e*256+i] = coef[b][e] * x[t][b][i]   (bf16, [8192][1024])
__global__ void prep_a1(const float* __restrict__ x, const float* __restrict__ coef,
                        bf16* __restrict__ A1) {
    int idx = blockIdx.x * 256 + threadIdx.x;          // 8192*1024
    int row = idx >> 10, k = idx & 1023;
    int b = row & 63;
    int e = k >> 8, i = k & 255;
    A1[idx] = __float2bfloat16(coef[(b << 2) + e] * x[((size_t)row << 8) + i]);
}

// biasmix[b][o] = sum_e coef[b][e]*(bi[e][o]+bh[e][o])   (f32, [64][2048])
__global__ void prep_bias(const float* __restrict__ coef, const float* __restrict__ bi,
                          const float* __restrict__ bh, float* __restrict__ biasmix) {
    int idx = blockIdx.x * 256 + threadIdx.x;          // 64*2048
    int b = idx >> 11, o = idx & 2047;
    float s = 0.f;
#pragma unroll
    for (int e = 0; e < 4; ++e)
        s += coef[(b << 2) + e] * (bi[(e << 11) + o] + bh[(e << 11) + o]);
    biasmix[idx] = s;
}

// z0[b][e*512+j] = coef[b][e]*h0[b][j]   (bf16, ping-pong buffer 0); also zero barrier
__global__ void prep_z0(const float* __restrict__ h0, const float* __restrict__ coef,
                        bf16* __restrict__ z, unsigned* __restrict__ cnt) {
    int idx = blockIdx.x * 256 + threadIdx.x;          // 64*2048
    if (idx == 0) *cnt = 0u;
    int b = idx >> 11, k = idx & 2047;
    int e = k >> 9, j = k & 511;
    z[idx] = __float2bfloat16(coef[(b << 2) + e] * h0[(b << 9) + j]);
}

// ---------------- main recurrent kernel ----------------
// 128 WGs x 256 threads. WG wg owns hidden units j0=4*wg .. j0+3, i.e. the 16
// gate columns o = q*512 + j0 + jj (q=gate 0..3, jj=0..3). Weight slices live
// in LDS across all 128 steps; c-state lives in registers. Grid barrier is a
// single-counter epoch barrier in d_ws (cg::sync measured ~40us/step in R1).

__launch_bounds__(256, 1)
__global__ void lstm_rec(const bf16* __restrict__ W2T, const bf16* __restrict__ W1T,
                         const bf16* __restrict__ A1, const float* __restrict__ biasmix,
                         bf16* z, const float* __restrict__ coef,
                         const float* __restrict__ c0, float* __restrict__ out,
                         unsigned* __restrict__ bar) {
    constexpr int SP2 = 2048 + 8;
    constexpr int SP1 = 1024 + 8;
    __shared__ bf16  Wsl [16][SP2];   // [col n][k]  (B operand, K-major rows)
    __shared__ bf16  W1sl[16][SP1];
    __shared__ float g_lds [64][17];
    __shared__ float bias_l[64][17];

    const int wg  = blockIdx.x;       // 0..127
    const int j0  = wg << 2;
    const int tid = threadIdx.x;
    const int lane = tid & 63;
    const int wv  = tid >> 6;         // wave 0..3 -> rows 16*wv..+15

    // ---- load weight slices into LDS (once) ----
#pragma unroll 1
    for (int n = 0; n < 16; ++n) {
        int o = ((n >> 2) << 9) + j0 + (n & 3);
        const bf16* s2 = W2T + ((size_t)o << 11);
        for (int k = tid; k < 2048; k += 256) Wsl[n][k] = s2[k];
        const bf16* s1 = W1T + ((size_t)o << 10);
        for (int k = tid; k < 1024; k += 256) W1sl[n][k] = s1[k];
    }
    for (int idx = tid; idx < 64 * 16; idx += 256) {
        int b = idx >> 4, n = idx & 15;
        int o = ((n >> 2) << 9) + j0 + (n & 3);
        bias_l[b][n] = biasmix[(b << 11) + o];
    }

    // ---- per-thread gate-phase state: tid -> (b_g, jj) ----
    const int b_g = tid >> 2, jj = tid & 3;
    float c_reg = c0[(b_g << 9) + j0 + jj];
    const float cf0 = coef[(b_g << 2) + 0];
    const float cf1 = coef[(b_g << 2) + 1];
    const float cf2 = coef[(b_g << 2) + 2];
    const float cf3 = coef[(b_g << 2) + 3];

    // MFMA lane mapping (16x16x32): A row = lane&15, k-group = lane>>4 (8 contig k)
    const int rlo  = lane & 15;
    const int kg   = lane >> 4;
    const int arow = (wv << 4) + rlo;   // sample index this lane loads for A

    __syncthreads();

    f32x4 acc0, acc1, acc2, acc3;
    // ---- input-part GEMM for step 0 (A1 ready; overlaps nothing yet) ----
    {
        const bf16* xa = A1 + ((size_t)arow << 10) + (kg << 3);
        acc0 = (f32x4){0.f, 0.f, 0.f, 0.f}; acc1 = acc0; acc2 = acc0; acc3 = acc0;
#pragma unroll
        for (int kk = 0; kk < 32; kk += 4) {
            bf16x8 a0 = *(const bf16x8*)(xa + (kk + 0) * 32);
            bf16x8 a1 = *(const bf16x8*)(xa + (kk + 1) * 32);
            bf16x8 a2 = *(const bf16x8*)(xa + (kk + 2) * 32);
            bf16x8 a3 = *(const bf16x8*)(xa + (kk + 3) * 32);
            bf16x8 b0 = *(const bf16x8*)(&W1sl[rlo][(kk + 0) * 32 + (kg << 3)]);
            bf16x8 b1 = *(const bf16x8*)(&W1sl[rlo][(kk + 1) * 32 + (kg << 3)]);
            bf16x8 b2 = *(const bf16x8*)(&W1sl[rlo][(kk + 2) * 32 + (kg << 3)]);
            bf16x8 b3 = *(const bf16x8*)(&W1sl[rlo][(kk + 3) * 32 + (kg << 3)]);
            acc0 = __builtin_amdgcn_mfma_f32_16x16x32_bf16(a0, b0, acc0, 0, 0, 0);
            acc1 = __builtin_amdgcn_mfma_f32_16x16x32_bf16(a1, b1, acc1, 0, 0, 0);
            acc2 = __builtin_amdgcn_mfma_f32_16x16x32_bf16(a2, b2, acc2, 0, 0, 0);
            acc3 = __builtin_amdgcn_mfma_f32_16x16x32_bf16(a3, b3, acc3, 0, 0, 0);
        }
    }

    for (int t = 0; t < T_STEPS; ++t) {
        // ---- wait for epoch t (all z(t) writes visible) ----
        if (t) {
            if (tid == 0) {
                const unsigned target = (unsigned)NWG * (unsigned)t;
                while (__hip_atomic_load(bar, __ATOMIC_RELAXED, __HIP_MEMORY_SCOPE_AGENT) < target)
                    __builtin_amdgcn_s_sleep(1);
            }
            __syncthreads();
            __threadfence();   // acquire: invalidate stale L1/L2 before z reads
        }

        const bf16* zin  = z + ((size_t)(t & 1) << 17);    // 64*2048 elems/buf
        bf16*       zout = z + ((size_t)((t + 1) & 1) << 17);
        const bf16* za = zin + ((size_t)arow << 11) + (kg << 3);

        // hidden part: K = 2048 -> 64 MFMA k-steps, accumulate onto input part
#pragma unroll
        for (int kk = 0; kk < 64; kk += 4) {
            bf16x8 a0 = *(const bf16x8*)(za + (kk + 0) * 32);
            bf16x8 a1 = *(const bf16x8*)(za + (kk + 1) * 32);
            bf16x8 a2 = *(const bf16x8*)(za + (kk + 2) * 32);
            bf16x8 a3 = *(const bf16x8*)(za + (kk + 3) * 32);
            bf16x8 b0 = *(const bf16x8*)(&Wsl[rlo][(kk + 0) * 32 + (kg << 3)]);
            bf16x8 b1 = *(const bf16x8*)(&Wsl[rlo][(kk + 1) * 32 + (kg << 3)]);
            bf16x8 b2 = *(const bf16x8*)(&Wsl[rlo][(kk + 2) * 32 + (kg << 3)]);
            bf16x8 b3 = *(const bf16x8*)(&Wsl[rlo][(kk + 3) * 32 + (kg << 3)]);
            acc0 = __builtin_amdgcn_mfma_f32_16x16x32_bf16(a0, b0, acc0, 0, 0, 0);
            acc1 = __builtin_amdgcn_mfma_f32_16x16x32_bf16(a1, b1, acc1, 0, 0, 0);
            acc2 = __builtin_amdgcn_mfma_f32_16x16x32_bf16(a2, b2, acc2, 0, 0, 0);
            acc3 = __builtin_amdgcn_mfma_f32_16x16x32_bf16(a3, b3, acc3, 0, 0, 0);
        }
        f32x4 g4 = (acc0 + acc1) + (acc2 + acc3);

        // C/D layout: col = lane&15, row = 4*(lane>>4) + r   (verified m89)
        const int brow = (wv << 4) + (kg << 2);
#pragma unroll
        for (int r = 0; r < 4; ++r)
            g_lds[brow + r][rlo] = g4[r] + bias_l[brow + r][rlo];
        __syncthreads();

        // ---- gate phase: thread (b_g, jj) ----
        float gi = g_lds[b_g][jj];
        float gf = g_lds[b_g][4 + jj];
        float gc = g_lds[b_g][8 + jj];
        float go = g_lds[b_g][12 + jj];
        float ig = 1.f / (1.f + __expf(-gi));
        float fg = 1.f / (1.f + __expf(-gf));
        float cc = tanhf(gc);
        float og = 1.f / (1.f + __expf(-go));
        float cn = fg * c_reg + ig * cc;
        float h  = og * tanhf(cn);
        c_reg = cn;

        out[((size_t)t << 15) + (b_g << 9) + j0 + jj] = h;
        const int zo = (b_g << 11) + j0 + jj;
        zout[zo       ] = __float2bfloat16(cf0 * h);
        zout[zo +  512] = __float2bfloat16(cf1 * h);
        zout[zo + 1024] = __float2bfloat16(cf2 * h);
        zout[zo + 1536] = __float2bfloat16(cf3 * h);
        if (t == T_STEPS - 1) {
            size_t base = (size_t)T_STEPS << 15;
            out[base + (b_g << 9) + j0 + jj] = h;
            out[base + (1 << 15) + (b_g << 9) + j0 + jj] = cn;
        }

        // ---- arrive: release z(t+1) ----
        __syncthreads();   // drains vmcnt: all zout stores in L2
        __threadfence();   // agent-scope release (L2 writeback for cross-XCD)
        if (tid == 0)
            __hip_atomic_fetch_add(bar, 1u, __ATOMIC_RELEASE, __HIP_MEMORY_SCOPE_AGENT);

        // ---- overlap: input-part GEMM for step t+1 (independent of z) ----
        if (t + 1 < T_STEPS) {
            const bf16* xa = A1 + ((size_t)(((t + 1) << 6) + arow) << 10) + (kg << 3);
            acc0 = (f32x4){0.f, 0.f, 0.f, 0.f}; acc1 = acc0; acc2 = acc0; acc3 = acc0;
#pragma unroll
            for (int kk = 0; kk < 32; kk += 4) {
                bf16x8 a0 = *(const bf16x8*)(xa + (kk + 0) * 32);
                bf16x8 a1 = *(const bf16x8*)(xa + (kk + 1) * 32);
                bf16x8 a2 = *(const bf16x8*)(xa + (kk + 2) * 32);
                bf16x8 a3 = *(const bf16x8*)(xa + (kk + 3) * 32);
                bf16x8 b0 = *(const bf16x8*)(&W1sl[rlo][(kk + 0) * 32 + (kg << 3)]);
                bf16x8 b1 = *(const bf16x8*)(&W1sl[rlo][(kk + 1) * 32 + (kg << 3)]);
                bf16x8 b2 = *(const bf16x8*)(&W1sl[rlo][(kk + 2) * 32 + (kg << 3)]);
                bf16x8 b3 = *(const bf16x8*)(&W1sl[rlo][(kk + 3) * 32 + (kg << 3)]);
                acc0 = __builtin_amdgcn_mfma_f32_16x16x32_bf16(a0, b0, acc0, 0, 0, 0);
                acc1 = __builtin_amdgcn_mfma_f32_16x16x32_bf16(a1, b1, acc1, 0, 0, 0);
                acc2 = __builtin_amdgcn_mfma_f32_16x16x32_bf16(a2, b2, acc2, 0, 0, 0);
                acc3 = __builtin_amdgcn_mfma_f32_16x16x32_bf16(a3, b3, acc3, 0, 0, 0);
            }
        }
    }
}

// ---------------- launch ----------------
extern "C" void kernel_launch(void* const* d_in, const int* in_sizes, int n_in,
                              void* d_out, int out_size, void* d_ws, size_t ws_size,
                              hipStream_t stream) {
    const float* x    = (const float*)d_in[0];
    const float* h0   = (const float*)d_in[1];
    const float* c0   = (const float*)d_in[2];
    const float* coef = (const float*)d_in[3];
    const float* Wi   = (const float*)d_in[4];
    const float* bi   = (const float*)d_in[5];
    const float* Wh   = (const float*)d_in[6];
    const float* bh   = (const float*)d_in[7];
    float* out = (float*)d_out;

    char* ws = (char*)d_ws;
    bf16*  W2T     = (bf16*)(ws);                                   // 8 MB
    bf16*  W1T     = (bf16*)(ws + (8u  << 20));                     // 4 MB
    bf16*  A1      = (bf16*)(ws + (12u << 20));                     // 16 MB
    float* biasmix = (float*)(ws + (28u << 20));                    // 512 KB
    bf16*  z       = (bf16*)(ws + (28u << 20) + (512u << 10));      // 512 KB (2 bufs)
    unsigned* bar  = (unsigned*)(ws + (29u << 20));                 // 4 B barrier

    prep_w2t <<<16384, 256, 0, stream>>>(Wh, W2T);
    prep_w1t <<< 8192, 256, 0, stream>>>(Wi, W1T);
    prep_a1  <<<32768, 256, 0, stream>>>(x, coef, A1);
    prep_bias<<<  512, 256, 0, stream>>>(coef, bi, bh, biasmix);
    prep_z0  <<<  512, 256, 0, stream>>>(h0, coef, z, bar);

    void* args[] = {(void*)&W2T, (void*)&W1T, (void*)&A1, (void*)&biasmix,
                    (void*)&z, (void*)&coef, (void*)&c0, (void*)&out, (void*)&bar};
    hipLaunchCooperativeKernel((void*)lstm_rec, dim3(128), dim3(256), args, 0, stream);
}

// Round 3
// 2881.545 us; speedup vs baseline: 1.9909x; 1.5441x over previous
//
#include <hip/hip_runtime.h>
#include <hip/hip_bf16.h>

typedef __hip_bfloat16 bf16;
typedef __attribute__((ext_vector_type(8))) short bf16x8;
typedef __attribute__((ext_vector_type(4))) float f32x4;

#define T_STEPS 128
#define NWG 128
// B=64, I=256, H=512, E=4, G=2048(=4H), K2=E*H=2048, K1=E*I=1024
// z layout: z[b][4*j + e] = coef[b][e]*h[b][j]  (so the gate-phase write of one
// hidden unit's 4 expert-scaled copies is a single contiguous 8B store)

__device__ inline unsigned short f2bf(float f) {
    bf16 b = __float2bfloat16(f);
    return *reinterpret_cast<unsigned short*>(&b);
}

// ---------------- prep kernels ----------------

// W2T[o][4*j+e] = Wh[e][o][j]   (bf16, [2048][2048])
__global__ void prep_w2t(const float* __restrict__ Wh, bf16* __restrict__ W2T) {
    int idx = blockIdx.x * 256 + threadIdx.x;          // 2048*2048
    int o = idx >> 11, k = idx & 2047;
    int j = k >> 2, e = k & 3;
    W2T[idx] = __float2bfloat16(Wh[((size_t)((e << 11) + o) << 9) + j]);
}

// W1T[o][e*256+i] = Wi[e][o][i]     (bf16, [2048][1024])
__global__ void prep_w1t(const float* __restrict__ Wi, bf16* __restrict__ W1T) {
    int idx = blockIdx.x * 256 + threadIdx.x;          // 2048*1024
    int o = idx >> 10, k = idx & 1023;
    int e = k >> 8, i = k & 255;
    W1T[idx] = __float2bfloat16(Wi[((size_t)((e << 11) + o) << 8) + i]);
}

// A1[t*64+b][e*256+i] = coef[b][e] * x[t][b][i]   (bf16, [8192][1024])
__global__ void prep_a1(const float* __restrict__ x, const float* __restrict__ coef,
                        bf16* __restrict__ A1) {
    int idx = blockIdx.x * 256 + threadIdx.x;          // 8192*1024
    int row = idx >> 10, k = idx & 1023;
    int b = row & 63;
    int e = k >> 8, i = k & 255;
    A1[idx] = __float2bfloat16(coef[(b << 2) + e] * x[((size_t)row << 8) + i]);
}

// biasmix[b][o] = sum_e coef[b][e]*(bi[e][o]+bh[e][o])   (f32, [64][2048])
__global__ void prep_bias(const float* __restrict__ coef, const float* __restrict__ bi,
                          const float* __restrict__ bh, float* __restrict__ biasmix) {
    int idx = blockIdx.x * 256 + threadIdx.x;          // 64*2048
    int b = idx >> 11, o = idx & 2047;
    float s = 0.f;
#pragma unroll
    for (int e = 0; e < 4; ++e)
        s += coef[(b << 2) + e] * (bi[(e << 11) + o] + bh[(e << 11) + o]);
    biasmix[idx] = s;
}

// z0[b][4j+e] = coef[b][e]*h0[b][j]; also zero the 128 barrier flags
__global__ void prep_z0(const float* __restrict__ h0, const float* __restrict__ coef,
                        bf16* __restrict__ z, unsigned* __restrict__ flags) {
    int idx = blockIdx.x * 256 + threadIdx.x;          // 64*2048
    if (idx < NWG) flags[idx] = 0u;
    int b = idx >> 11, k = idx & 2047;
    int j = k >> 2, e = k & 3;
    z[idx] = __float2bfloat16(coef[(b << 2) + e] * h0[(b << 9) + j]);
}

// ---------------- main recurrent kernel ----------------
// 128 WGs x 256 threads (1 WG/CU). WG wg owns hidden units j0=4*wg..j0+3, i.e.
// the 16 gate columns o = q*512 + j0 + jj. Weight slices live in LDS across
// all 128 steps; c-state lives in registers.
// Sync per step: flag-array barrier (no RMW), ONE threadfence per WG per side
// (R2 had 256 threads x 2 fences/step = L2-wide inv/wbl2 storm -> 34.7us/step).

__launch_bounds__(256, 1)
__global__ void lstm_rec(const bf16* __restrict__ W2T, const bf16* __restrict__ W1T,
                         const bf16* __restrict__ A1, const float* __restrict__ biasmix,
                         bf16* z, const float* __restrict__ coef,
                         const float* __restrict__ c0, float* __restrict__ out,
                         unsigned* __restrict__ flags) {
    constexpr int SP2 = 2048 + 8;
    constexpr int SP1 = 1024 + 8;
    __shared__ bf16  Wsl [16][SP2];   // [col n][k']  (B operand, K-major)
    __shared__ bf16  W1sl[16][SP1];
    __shared__ float g_lds [64][17];
    __shared__ float bias_l[64][17];

    const int wg  = blockIdx.x;       // 0..127
    const int j0  = wg << 2;
    const int tid = threadIdx.x;
    const int lane = tid & 63;
    const int wv  = tid >> 6;         // wave 0..3 -> rows 16*wv..+15

    // ---- load weight slices into LDS (once) ----
#pragma unroll 1
    for (int n = 0; n < 16; ++n) {
        int o = ((n >> 2) << 9) + j0 + (n & 3);
        const bf16* s2 = W2T + ((size_t)o << 11);
        for (int k = tid; k < 2048; k += 256) Wsl[n][k] = s2[k];
        const bf16* s1 = W1T + ((size_t)o << 10);
        for (int k = tid; k < 1024; k += 256) W1sl[n][k] = s1[k];
    }
    for (int idx = tid; idx < 64 * 16; idx += 256) {
        int b = idx >> 4, n = idx & 15;
        int o = ((n >> 2) << 9) + j0 + (n & 3);
        bias_l[b][n] = biasmix[(b << 11) + o];
    }

    // ---- per-thread gate-phase state: tid -> (b_g, jj) ----
    const int b_g = tid >> 2, jj = tid & 3;
    float c_reg = c0[(b_g << 9) + j0 + jj];
    const float cf0 = coef[(b_g << 2) + 0];
    const float cf1 = coef[(b_g << 2) + 1];
    const float cf2 = coef[(b_g << 2) + 2];
    const float cf3 = coef[(b_g << 2) + 3];

    // MFMA lane mapping (16x16x32): A row = lane&15, k-group = lane>>4
    const int rlo  = lane & 15;
    const int kg   = lane >> 4;
    const int arow = (wv << 4) + rlo;

    __syncthreads();

    f32x4 acc0, acc1, acc2, acc3;   // input-part accumulators (overlap slot)
    {
        const bf16* xa = A1 + ((size_t)arow << 10) + (kg << 3);
        acc0 = (f32x4){0.f, 0.f, 0.f, 0.f}; acc1 = acc0; acc2 = acc0; acc3 = acc0;
#pragma unroll
        for (int kk = 0; kk < 32; ++kk) {
            bf16x8 a = *(const bf16x8*)(xa + kk * 32);
            bf16x8 b = *(const bf16x8*)(&W1sl[rlo][kk * 32 + (kg << 3)]);
            f32x4& ac = (kk & 3) == 0 ? acc0 : (kk & 3) == 1 ? acc1 : (kk & 3) == 2 ? acc2 : acc3;
            ac = __builtin_amdgcn_mfma_f32_16x16x32_bf16(a, b, ac, 0, 0, 0);
        }
    }

    for (int t = 0; t < T_STEPS; ++t) {
        // ---- wait for epoch t ----
        if (t) {
            if (tid < NWG) {
                while (__hip_atomic_load(&flags[tid], __ATOMIC_RELAXED,
                                         __HIP_MEMORY_SCOPE_AGENT) < (unsigned)t)
                    __builtin_amdgcn_s_sleep(1);
            }
            __syncthreads();                 // all 128 flags confirmed
            if (tid < 64) __threadfence();   // ONE inv/wbl2 for the whole WG
            __syncthreads();
        }

        const bf16* zin  = z + ((size_t)(t & 1) << 17);    // 64*2048 elems/buf
        bf16*       zout = z + ((size_t)((t + 1) & 1) << 17);
        const bf16* za = zin + ((size_t)arow << 11) + (kg << 3);

        // hidden part: K=2048 -> 64 MFMA k-steps, 8-way accumulator rotation
        f32x4 ah[8];
#pragma unroll
        for (int i = 0; i < 8; ++i) ah[i] = (f32x4){0.f, 0.f, 0.f, 0.f};
#pragma unroll
        for (int kk = 0; kk < 64; ++kk) {
            bf16x8 a = *(const bf16x8*)(za + kk * 32);
            bf16x8 b = *(const bf16x8*)(&Wsl[rlo][kk * 32 + (kg << 3)]);
            ah[kk & 7] = __builtin_amdgcn_mfma_f32_16x16x32_bf16(a, b, ah[kk & 7], 0, 0, 0);
        }
        f32x4 g4 = (((ah[0] + ah[1]) + (ah[2] + ah[3])) + ((ah[4] + ah[5]) + (ah[6] + ah[7])))
                 + ((acc0 + acc1) + (acc2 + acc3));

        // C/D layout: col = lane&15, row = 4*(lane>>4) + r   (verified m89)
        const int brow = (wv << 4) + (kg << 2);
#pragma unroll
        for (int r = 0; r < 4; ++r)
            g_lds[brow + r][rlo] = g4[r] + bias_l[brow + r][rlo];
        __syncthreads();

        // ---- gate phase: thread (b_g, jj) ----
        float gi = g_lds[b_g][jj];
        float gf = g_lds[b_g][4 + jj];
        float gc = g_lds[b_g][8 + jj];
        float go = g_lds[b_g][12 + jj];
        float ig = 1.f / (1.f + __expf(-gi));
        float fg = 1.f / (1.f + __expf(-gf));
        float cc = tanhf(gc);
        float og = 1.f / (1.f + __expf(-go));
        float cn = fg * c_reg + ig * cc;
        float h  = og * tanhf(cn);
        c_reg = cn;

        // z[b][4*(j0+jj) + e], e=0..3 -> one contiguous 8B store
        {
            unsigned u0 = f2bf(cf0 * h) | ((unsigned)f2bf(cf1 * h) << 16);
            unsigned u1 = f2bf(cf2 * h) | ((unsigned)f2bf(cf3 * h) << 16);
            uint2 pk = {u0, u1};
            *(uint2*)(zout + (b_g << 11) + ((j0 + jj) << 2)) = pk;
        }

        // ---- arrive: drain WG stores to L2, single wbl2, flag release ----
        __syncthreads();
        if (tid == 0) {
            __threadfence();
            __hip_atomic_store(&flags[wg], (unsigned)(t + 1), __ATOMIC_RELEASE,
                               __HIP_MEMORY_SCOPE_AGENT);
        }

        // ---- post-arrive (overlaps other WGs' skew): out stores + next input GEMM
        out[((size_t)t << 15) + (b_g << 9) + j0 + jj] = h;
        if (t == T_STEPS - 1) {
            size_t base = (size_t)T_STEPS << 15;
            out[base + (b_g << 9) + j0 + jj] = h;
            out[base + (1 << 15) + (b_g << 9) + j0 + jj] = cn;
        }
        if (t + 1 < T_STEPS) {
            const bf16* xa = A1 + ((size_t)(((t + 1) << 6) + arow) << 10) + (kg << 3);
            acc0 = (f32x4){0.f, 0.f, 0.f, 0.f}; acc1 = acc0; acc2 = acc0; acc3 = acc0;
#pragma unroll
            for (int kk = 0; kk < 32; ++kk) {
                bf16x8 a = *(const bf16x8*)(xa + kk * 32);
                bf16x8 b = *(const bf16x8*)(&W1sl[rlo][kk * 32 + (kg << 3)]);
                f32x4& ac = (kk & 3) == 0 ? acc0 : (kk & 3) == 1 ? acc1 : (kk & 3) == 2 ? acc2 : acc3;
                ac = __builtin_amdgcn_mfma_f32_16x16x32_bf16(a, b, ac, 0, 0, 0);
            }
        }
    }
}

// ---------------- launch ----------------
extern "C" void kernel_launch(void* const* d_in, const int* in_sizes, int n_in,
                              void* d_out, int out_size, void* d_ws, size_t ws_size,
                              hipStream_t stream) {
    const float* x    = (const float*)d_in[0];
    const float* h0   = (const float*)d_in[1];
    const float* c0   = (const float*)d_in[2];
    const float* coef = (const float*)d_in[3];
    const float* Wi   = (const float*)d_in[4];
    const float* bi   = (const float*)d_in[5];
    const float* Wh   = (const float*)d_in[6];
    const float* bh   = (const float*)d_in[7];
    float* out = (float*)d_out;

    char* ws = (char*)d_ws;
    bf16*  W2T     = (bf16*)(ws);                                   // 8 MB
    bf16*  W1T     = (bf16*)(ws + (8u  << 20));                     // 4 MB
    bf16*  A1      = (bf16*)(ws + (12u << 20));                     // 16 MB
    float* biasmix = (float*)(ws + (28u << 20));                    // 512 KB
    bf16*  z       = (bf16*)(ws + (28u << 20) + (512u << 10));      // 512 KB (2 bufs)
    unsigned* flags= (unsigned*)(ws + (29u << 20));                 // 512 B

    prep_w2t <<<16384, 256, 0, stream>>>(Wh, W2T);
    prep_w1t <<< 8192, 256, 0, stream>>>(Wi, W1T);
    prep_a1  <<<32768, 256, 0, stream>>>(x, coef, A1);
    prep_bias<<<  512, 256, 0, stream>>>(coef, bi, bh, biasmix);
    prep_z0  <<<  512, 256, 0, stream>>>(h0, coef, z, flags);

    void* args[] = {(void*)&W2T, (void*)&W1T, (void*)&A1, (void*)&biasmix,
                    (void*)&z, (void*)&coef, (void*)&c0, (void*)&out, (void*)&flags};
    hipLaunchCooperativeKernel((void*)lstm_rec, dim3(128), dim3(256), args, 0, stream);
}

// Round 4
// 1661.106 us; speedup vs baseline: 3.4537x; 1.7347x over previous
//
#include <hip/hip_runtime.h>
#include <hip/hip_bf16.h>

typedef __hip_bfloat16 bf16;
typedef __attribute__((ext_vector_type(8))) short bf16x8;
typedef __attribute__((ext_vector_type(4))) float f32x4;

#define T_STEPS 128
#define NWG 128
#define ZSLOTS 8   // z rotation depth; acquire-inv fires every ZSLOTS steps
// B=64, I=256, H=512, E=4, G=2048(=4H), K2=E*H=2048, K1=E*I=1024
// z layout: z[b][4*j + e] = coef[b][e]*h[b][j]  (one 8B store per hidden unit)

__device__ inline unsigned short f2bf(float f) {
    bf16 b = __float2bfloat16(f);
    return *reinterpret_cast<unsigned short*>(&b);
}

// ---------------- prep kernels ----------------

// W2T[o][4*j+e] = Wh[e][o][j]   (bf16, [2048][2048])
__global__ void prep_w2t(const float* __restrict__ Wh, bf16* __restrict__ W2T) {
    int idx = blockIdx.x * 256 + threadIdx.x;          // 2048*2048
    int o = idx >> 11, k = idx & 2047;
    int j = k >> 2, e = k & 3;
    W2T[idx] = __float2bfloat16(Wh[((size_t)((e << 11) + o) << 9) + j]);
}

// W1T[o][e*256+i] = Wi[e][o][i]     (bf16, [2048][1024])
__global__ void prep_w1t(const float* __restrict__ Wi, bf16* __restrict__ W1T) {
    int idx = blockIdx.x * 256 + threadIdx.x;          // 2048*1024
    int o = idx >> 10, k = idx & 1023;
    int e = k >> 8, i = k & 255;
    W1T[idx] = __float2bfloat16(Wi[((size_t)((e << 11) + o) << 8) + i]);
}

// A1[t*64+b][e*256+i] = coef[b][e] * x[t][b][i]   (bf16, [8192][1024])
__global__ void prep_a1(const float* __restrict__ x, const float* __restrict__ coef,
                        bf16* __restrict__ A1) {
    int idx = blockIdx.x * 256 + threadIdx.x;          // 8192*1024
    int row = idx >> 10, k = idx & 1023;
    int b = row & 63;
    int e = k >> 8, i = k & 255;
    A1[idx] = __float2bfloat16(coef[(b << 2) + e] * x[((size_t)row << 8) + i]);
}

// biasmix[b][o] = sum_e coef[b][e]*(bi[e][o]+bh[e][o])   (f32, [64][2048])
__global__ void prep_bias(const float* __restrict__ coef, const float* __restrict__ bi,
                          const float* __restrict__ bh, float* __restrict__ biasmix) {
    int idx = blockIdx.x * 256 + threadIdx.x;          // 64*2048
    int b = idx >> 11, o = idx & 2047;
    float s = 0.f;
#pragma unroll
    for (int e = 0; e < 4; ++e)
        s += coef[(b << 2) + e] * (bi[(e << 11) + o] + bh[(e << 11) + o]);
    biasmix[idx] = s;
}

// z0[b][4j+e] = coef[b][e]*h0[b][j] (slot 0); also zero the 128 barrier flags
__global__ void prep_z0(const float* __restrict__ h0, const float* __restrict__ coef,
                        bf16* __restrict__ z, unsigned* __restrict__ flags) {
    int idx = blockIdx.x * 256 + threadIdx.x;          // 64*2048
    if (idx < NWG) flags[idx] = 0u;
    int b = idx >> 11, k = idx & 2047;
    int j = k >> 2, e = k & 3;
    z[idx] = __float2bfloat16(coef[(b << 2) + e] * h0[(b << 9) + j]);
}

// ---------------- main recurrent kernel ----------------
// 128 WGs x 256 threads (1 WG/CU). WG wg owns hidden units j0=4*wg..j0+3 (16
// gate columns). Weights in LDS for all 128 steps; c-state in registers.
// Sync design (R4): NO wbl2 anywhere in the loop. z writes are agent-scope
// relaxed atomic 8B stores (sc1 write-through to LLC); release = vmcnt(0) +
// flag store. z reads are plain cached; staleness handled by 8-slot z rotation
// + acquire-only fence (buffer_inv, no wbl2) every 8th step by one wave.
// (R3: 2 acq_rel fences/WG/step = 32 L2-maintenance ops/XCD/step ~= 22us/step.)

__launch_bounds__(256, 1)
__global__ void lstm_rec(const bf16* __restrict__ W2T, const bf16* __restrict__ W1T,
                         const bf16* __restrict__ A1, const float* __restrict__ biasmix,
                         bf16* z, const float* __restrict__ coef,
                         const float* __restrict__ c0, float* __restrict__ out,
                         unsigned* __restrict__ flags) {
    constexpr int SP2 = 2048 + 8;
    constexpr int SP1 = 1024 + 8;
    __shared__ bf16  Wsl [16][SP2];   // [col n][k']  (B operand, K-major)
    __shared__ bf16  W1sl[16][SP1];
    __shared__ float g_lds [64][17];
    __shared__ float bias_l[64][17];

    const int wg  = blockIdx.x;       // 0..127
    const int j0  = wg << 2;
    const int tid = threadIdx.x;
    const int lane = tid & 63;
    const int wv  = tid >> 6;         // wave 0..3 -> rows 16*wv..+15

    // ---- load weight slices into LDS (once) ----
#pragma unroll 1
    for (int n = 0; n < 16; ++n) {
        int o = ((n >> 2) << 9) + j0 + (n & 3);
        const bf16* s2 = W2T + ((size_t)o << 11);
        for (int k = tid; k < 2048; k += 256) Wsl[n][k] = s2[k];
        const bf16* s1 = W1T + ((size_t)o << 10);
        for (int k = tid; k < 1024; k += 256) W1sl[n][k] = s1[k];
    }
    for (int idx = tid; idx < 64 * 16; idx += 256) {
        int b = idx >> 4, n = idx & 15;
        int o = ((n >> 2) << 9) + j0 + (n & 3);
        bias_l[b][n] = biasmix[(b << 11) + o];
    }

    // ---- per-thread gate-phase state: tid -> (b_g, jj) ----
    const int b_g = tid >> 2, jj = tid & 3;
    float c_reg = c0[(b_g << 9) + j0 + jj];
    const float cf0 = coef[(b_g << 2) + 0];
    const float cf1 = coef[(b_g << 2) + 1];
    const float cf2 = coef[(b_g << 2) + 2];
    const float cf3 = coef[(b_g << 2) + 3];

    // MFMA lane mapping (16x16x32): A row = lane&15, k-group = lane>>4
    const int rlo  = lane & 15;
    const int kg   = lane >> 4;
    const int arow = (wv << 4) + rlo;

    __syncthreads();

    f32x4 acc0, acc1, acc2, acc3;   // input-part accumulators (overlap slot)
    {
        const bf16* xa = A1 + ((size_t)arow << 10) + (kg << 3);
        acc0 = (f32x4){0.f, 0.f, 0.f, 0.f}; acc1 = acc0; acc2 = acc0; acc3 = acc0;
#pragma unroll
        for (int kk = 0; kk < 32; ++kk) {
            bf16x8 a = *(const bf16x8*)(xa + kk * 32);
            bf16x8 b = *(const bf16x8*)(&W1sl[rlo][kk * 32 + (kg << 3)]);
            f32x4& ac = (kk & 3) == 0 ? acc0 : (kk & 3) == 1 ? acc1 : (kk & 3) == 2 ? acc2 : acc3;
            ac = __builtin_amdgcn_mfma_f32_16x16x32_bf16(a, b, ac, 0, 0, 0);
        }
    }

    for (int t = 0; t < T_STEPS; ++t) {
        // ---- wait for epoch t; amortized acquire-inv (no wbl2) ----
        if (t) {
            if (tid < NWG) {
                while (__hip_atomic_load(&flags[tid], __ATOMIC_RELAXED,
                                         __HIP_MEMORY_SCOPE_AGENT) < (unsigned)t)
                    __builtin_amdgcn_s_sleep(1);
            }
        }
        if (((t & (ZSLOTS - 1)) == 0) && tid < 64)
            __builtin_amdgcn_fence(__ATOMIC_ACQUIRE, "agent");  // buffer_inv only
        __syncthreads();

        const bf16* zin  = z + ((size_t)(t & (ZSLOTS - 1)) << 17);       // 256KB/slot
        bf16*       zout = z + ((size_t)((t + 1) & (ZSLOTS - 1)) << 17);
        const bf16* za = zin + ((size_t)arow << 11) + (kg << 3);

        // hidden part: K=2048 -> 64 MFMA k-steps, 8-way accumulator rotation
        f32x4 ah[8];
#pragma unroll
        for (int i = 0; i < 8; ++i) ah[i] = (f32x4){0.f, 0.f, 0.f, 0.f};
#pragma unroll
        for (int kk = 0; kk < 64; ++kk) {
            bf16x8 a = *(const bf16x8*)(za + kk * 32);
            bf16x8 b = *(const bf16x8*)(&Wsl[rlo][kk * 32 + (kg << 3)]);
            ah[kk & 7] = __builtin_amdgcn_mfma_f32_16x16x32_bf16(a, b, ah[kk & 7], 0, 0, 0);
        }
        f32x4 g4 = (((ah[0] + ah[1]) + (ah[2] + ah[3])) + ((ah[4] + ah[5]) + (ah[6] + ah[7])))
                 + ((acc0 + acc1) + (acc2 + acc3));

        // C/D layout: col = lane&15, row = 4*(lane>>4) + r   (verified m89)
        const int brow = (wv << 4) + (kg << 2);
#pragma unroll
        for (int r = 0; r < 4; ++r)
            g_lds[brow + r][rlo] = g4[r] + bias_l[brow + r][rlo];
        __syncthreads();

        // ---- gate phase: thread (b_g, jj) ----
        float gi = g_lds[b_g][jj];
        float gf = g_lds[b_g][4 + jj];
        float gc = g_lds[b_g][8 + jj];
        float go = g_lds[b_g][12 + jj];
        float ig = 1.f / (1.f + __expf(-gi));
        float fg = 1.f / (1.f + __expf(-gf));
        float cc = tanhf(gc);
        float og = 1.f / (1.f + __expf(-go));
        float cn = fg * c_reg + ig * cc;
        float h  = og * tanhf(cn);
        c_reg = cn;

        // z[b][4*(j0+jj)+e], e=0..3: one 8B agent-scope store (sc1 write-through,
        // reaches LLC -> no release wbl2 needed)
        {
            unsigned long long pk =
                  (unsigned long long)(f2bf(cf0 * h) | ((unsigned)f2bf(cf1 * h) << 16))
                | ((unsigned long long)(f2bf(cf2 * h) | ((unsigned)f2bf(cf3 * h) << 16)) << 32);
            unsigned long long* zq = (unsigned long long*)(zout + (b_g << 11) + ((j0 + jj) << 2));
            __hip_atomic_store(zq, pk, __ATOMIC_RELAXED, __HIP_MEMORY_SCOPE_AGENT);
        }

        // ---- release: per-wave drain of the sc1 stores, then flag ----
        asm volatile("s_waitcnt vmcnt(0)" ::: "memory");
        __syncthreads();
        if (tid == 0)
            __hip_atomic_store(&flags[wg], (unsigned)(t + 1), __ATOMIC_RELAXED,
                               __HIP_MEMORY_SCOPE_AGENT);

        // ---- post-arrive (overlaps other WGs' skew): out stores + next input GEMM
        out[((size_t)t << 15) + (b_g << 9) + j0 + jj] = h;
        if (t == T_STEPS - 1) {
            size_t base = (size_t)T_STEPS << 15;
            out[base + (b_g << 9) + j0 + jj] = h;
            out[base + (1 << 15) + (b_g << 9) + j0 + jj] = cn;
        }
        if (t + 1 < T_STEPS) {
            const bf16* xa = A1 + ((size_t)(((t + 1) << 6) + arow) << 10) + (kg << 3);
            acc0 = (f32x4){0.f, 0.f, 0.f, 0.f}; acc1 = acc0; acc2 = acc0; acc3 = acc0;
#pragma unroll
            for (int kk = 0; kk < 32; ++kk) {
                bf16x8 a = *(const bf16x8*)(xa + kk * 32);
                bf16x8 b = *(const bf16x8*)(&W1sl[rlo][kk * 32 + (kg << 3)]);
                f32x4& ac = (kk & 3) == 0 ? acc0 : (kk & 3) == 1 ? acc1 : (kk & 3) == 2 ? acc2 : acc3;
                ac = __builtin_amdgcn_mfma_f32_16x16x32_bf16(a, b, ac, 0, 0, 0);
            }
        }
    }
}

// ---------------- launch ----------------
extern "C" void kernel_launch(void* const* d_in, const int* in_sizes, int n_in,
                              void* d_out, int out_size, void* d_ws, size_t ws_size,
                              hipStream_t stream) {
    const float* x    = (const float*)d_in[0];
    const float* h0   = (const float*)d_in[1];
    const float* c0   = (const float*)d_in[2];
    const float* coef = (const float*)d_in[3];
    const float* Wi   = (const float*)d_in[4];
    const float* bi   = (const float*)d_in[5];
    const float* Wh   = (const float*)d_in[6];
    const float* bh   = (const float*)d_in[7];
    float* out = (float*)d_out;

    char* ws = (char*)d_ws;
    bf16*  W2T     = (bf16*)(ws);                                   // 8 MB
    bf16*  W1T     = (bf16*)(ws + (8u  << 20));                     // 4 MB
    bf16*  A1      = (bf16*)(ws + (12u << 20));                     // 16 MB
    float* biasmix = (float*)(ws + (28u << 20));                    // 512 KB
    bf16*  z       = (bf16*)(ws + (28u << 20) + (512u << 10));      // 2 MB (8 slots)
    unsigned* flags= (unsigned*)(ws + (30u << 20) + (512u << 10));  // 512 B

    prep_w2t <<<16384, 256, 0, stream>>>(Wh, W2T);
    prep_w1t <<< 8192, 256, 0, stream>>>(Wi, W1T);
    prep_a1  <<<32768, 256, 0, stream>>>(x, coef, A1);
    prep_bias<<<  512, 256, 0, stream>>>(coef, bi, bh, biasmix);
    prep_z0  <<<  512, 256, 0, stream>>>(h0, coef, z, flags);

    void* args[] = {(void*)&W2T, (void*)&W1T, (void*)&A1, (void*)&biasmix,
                    (void*)&z, (void*)&coef, (void*)&c0, (void*)&out, (void*)&flags};
    hipLaunchCooperativeKernel((void*)lstm_rec, dim3(128), dim3(256), args, 0, stream);
}

// Round 5
// 1110.125 us; speedup vs baseline: 5.1678x; 1.4963x over previous
//
#include <hip/hip_runtime.h>
#include <hip/hip_bf16.h>

typedef __hip_bfloat16 bf16;
typedef __attribute__((ext_vector_type(8))) short bf16x8;
typedef __attribute__((ext_vector_type(4))) float f32x4;

#define T_STEPS 128
#define NWG 128
#define ZSLOTS 8   // h-slot rotation depth; acquire-inv fires every ZSLOTS steps
// B=64, I=256, H=512, E=4, G=2048(=4H)
// Exchange buffer is h itself: h_buf[slot][b][j] bf16, 64KB/slot.
// Per-expert GEMM: acc_e[b,o] = sum_h h[b,h]*Wh[e,o,h]; epilogue applies
// g = sum_e coef[b,e]*acc_e + xg + bias  (coef mixing folded into f32 epilogue).

__device__ inline unsigned short f2bf(float f) {
    bf16 b = __float2bfloat16(f);
    return *reinterpret_cast<unsigned short*>(&b);
}

// ---------------- prep kernels ----------------

// W2T[o][e*512+hh] = Wh[e][o][hh]   (bf16, [2048][2048])
__global__ void prep_w2t(const float* __restrict__ Wh, bf16* __restrict__ W2T) {
    int idx = blockIdx.x * 256 + threadIdx.x;          // 2048*2048
    int o = idx >> 11, k = idx & 2047;
    int e = k >> 9, hh = k & 511;
    W2T[idx] = __float2bfloat16(Wh[((size_t)((e << 11) + o) << 9) + hh]);
}

// W1T[o][e*256+i] = Wi[e][o][i]     (bf16, [2048][1024])
__global__ void prep_w1t(const float* __restrict__ Wi, bf16* __restrict__ W1T) {
    int idx = blockIdx.x * 256 + threadIdx.x;          // 2048*1024
    int o = idx >> 10, k = idx & 1023;
    int e = k >> 8, i = k & 255;
    W1T[idx] = __float2bfloat16(Wi[((size_t)((e << 11) + o) << 8) + i]);
}

// A1[t*64+b][e*256+i] = coef[b][e] * x[t][b][i]   (bf16, [8192][1024])
__global__ void prep_a1(const float* __restrict__ x, const float* __restrict__ coef,
                        bf16* __restrict__ A1) {
    int idx = blockIdx.x * 256 + threadIdx.x;          // 8192*1024
    int row = idx >> 10, k = idx & 1023;
    int b = row & 63;
    int e = k >> 8, i = k & 255;
    A1[idx] = __float2bfloat16(coef[(b << 2) + e] * x[((size_t)row << 8) + i]);
}

// biasmix[b][o] = sum_e coef[b][e]*(bi[e][o]+bh[e][o])   (f32, [64][2048])
__global__ void prep_bias(const float* __restrict__ coef, const float* __restrict__ bi,
                          const float* __restrict__ bh, float* __restrict__ biasmix) {
    int idx = blockIdx.x * 256 + threadIdx.x;          // 64*2048
    int b = idx >> 11, o = idx & 2047;
    float s = 0.f;
#pragma unroll
    for (int e = 0; e < 4; ++e)
        s += coef[(b << 2) + e] * (bi[(e << 11) + o] + bh[(e << 11) + o]);
    biasmix[idx] = s;
}

// h0 -> slot 0 (bf16 [64][512]); zero the 128 barrier flags
__global__ void prep_h0(const float* __restrict__ h0, bf16* __restrict__ hbuf,
                        unsigned* __restrict__ flags) {
    int idx = blockIdx.x * 256 + threadIdx.x;          // 64*512 = 32768
    if (idx < NWG) flags[idx] = 0u;
    hbuf[idx] = __float2bfloat16(h0[idx]);
}

// ---------------- main recurrent kernel ----------------
// 128 WGs x 256 threads (1 WG/CU). WG wg owns hidden units j0=4*wg..j0+3 (16
// gate columns o = q*512 + j0 + jj). Weights in LDS (pre-swizzled linear
// fragment layout -> conflict-free ds_read_b128); c-state in registers.
// Sync (validated R4): sc1 relaxed stores + vmcnt(0) + flag array release;
// sleep-poll acquire; buffer_inv (acquire fence, no wbl2) every ZSLOTS steps;
// h rotated over ZSLOTS slots so cached lines are never reused stale.

__launch_bounds__(256, 1)
__global__ void lstm_rec(const bf16* __restrict__ W2T, const bf16* __restrict__ W1T,
                         const bf16* __restrict__ A1, const float* __restrict__ biasmix,
                         bf16* h_buf, const float* __restrict__ coef,
                         const float* __restrict__ c0, float* __restrict__ out,
                         unsigned* __restrict__ flags) {
    __shared__ bf16x8 W2L[4 * 16 * 64];   // [e][kk][lane] fragments, 64KB
    __shared__ bf16x8 W1L[32 * 64];       // [kk][lane] fragments, 32KB
    __shared__ float  g_lds [64][17];
    __shared__ float  bias_l[64][17];
    __shared__ float4 coefL[64];          // coef[b][0..3]
    __shared__ unsigned long long hpk[64]; // packed h row fragments (4x bf16)

    const int wg  = blockIdx.x;       // 0..127
    const int j0  = wg << 2;
    const int tid = threadIdx.x;
    const int lane = tid & 63;
    const int wv  = tid >> 6;         // wave 0..3 -> rows 16*wv..+15

    const int rlo  = lane & 15;       // MFMA col index (o within the 16)
    const int kg   = lane >> 4;       // k-group
    const int arow = (wv << 4) + rlo; // A-row (sample b) this lane loads

    // ---- build LDS weight fragments (once) ----
    // W2L[g = e*1024 + kk*64 + l] = W2T[o(rlo(l))][e*512 + kk*32 + kg(l)*8 ..+8]
    for (int g = tid; g < 4096; g += 256) {
        int e = g >> 10, kk = (g >> 6) & 15, l = g & 63;
        int rl = l & 15, kgg = l >> 4;
        int o = ((rl >> 2) << 9) + j0 + (rl & 3);
        W2L[g] = *(const bf16x8*)(W2T + ((size_t)o << 11) + (e << 9) + (kk << 5) + (kgg << 3));
    }
    // W1L[g = kk*64 + l] = W1T[o(rlo(l))][kk*32 + kg(l)*8 ..+8]
    for (int g = tid; g < 2048; g += 256) {
        int kk = g >> 6, l = g & 63;
        int rl = l & 15, kgg = l >> 4;
        int o = ((rl >> 2) << 9) + j0 + (rl & 3);
        W1L[g] = *(const bf16x8*)(W1T + ((size_t)o << 10) + (kk << 5) + (kgg << 3));
    }
    for (int idx = tid; idx < 64 * 16; idx += 256) {
        int b = idx >> 4, n = idx & 15;
        int o = ((n >> 2) << 9) + j0 + (n & 3);
        bias_l[b][n] = biasmix[(b << 11) + o];
    }
    if (tid < 64) coefL[tid] = *(const float4*)(coef + (tid << 2));

    // ---- per-thread gate-phase state: tid -> (b_g, jj) ----
    const int b_g = tid >> 2, jj = tid & 3;
    float c_reg = c0[(b_g << 9) + j0 + jj];

    __syncthreads();

    f32x4 acc0, acc1, acc2, acc3;   // input-part accumulators (overlap slot)
    {
        const bf16x8* xa = (const bf16x8*)A1 + ((size_t)arow << 7) + kg;
        acc0 = (f32x4){0.f, 0.f, 0.f, 0.f}; acc1 = acc0; acc2 = acc0; acc3 = acc0;
#pragma unroll
        for (int kk = 0; kk < 32; ++kk) {
            bf16x8 a = xa[kk << 2];
            bf16x8 b = W1L[(kk << 6) + lane];
            f32x4& ac = (kk & 3) == 0 ? acc0 : (kk & 3) == 1 ? acc1 : (kk & 3) == 2 ? acc2 : acc3;
            ac = __builtin_amdgcn_mfma_f32_16x16x32_bf16(a, b, ac, 0, 0, 0);
        }
    }

    for (int t = 0; t < T_STEPS; ++t) {
        // ---- wait for epoch t; amortized acquire-inv (no wbl2) ----
        if (t) {
            if (tid < NWG) {
                while (__hip_atomic_load(&flags[tid], __ATOMIC_RELAXED,
                                         __HIP_MEMORY_SCOPE_AGENT) < (unsigned)t)
                    __builtin_amdgcn_s_sleep(1);
            }
        }
        if (((t & (ZSLOTS - 1)) == 0) && tid < 64)
            __builtin_amdgcn_fence(__ATOMIC_ACQUIRE, "agent");  // buffer_inv only
        __syncthreads();

        const bf16* hin  = h_buf + ((size_t)(t & (ZSLOTS - 1)) << 15);       // 64KB slots
        bf16*       hout = h_buf + ((size_t)((t + 1) & (ZSLOTS - 1)) << 15);

        // hidden part: per-expert GEMM, K=512 each, shared A (16 loads/lane)
        f32x4 e0 = {0.f, 0.f, 0.f, 0.f}, e1 = e0, e2 = e0, e3 = e0;
        {
            const bf16x8* ha = (const bf16x8*)hin + (arow << 6) + kg;
#pragma unroll
            for (int kk = 0; kk < 16; ++kk) {
                bf16x8 a = ha[kk << 2];
                e0 = __builtin_amdgcn_mfma_f32_16x16x32_bf16(a, W2L[(kk << 6) + lane       ], e0, 0, 0, 0);
                e1 = __builtin_amdgcn_mfma_f32_16x16x32_bf16(a, W2L[(kk << 6) + lane + 1024], e1, 0, 0, 0);
                e2 = __builtin_amdgcn_mfma_f32_16x16x32_bf16(a, W2L[(kk << 6) + lane + 2048], e2, 0, 0, 0);
                e3 = __builtin_amdgcn_mfma_f32_16x16x32_bf16(a, W2L[(kk << 6) + lane + 3072], e3, 0, 0, 0);
            }
        }
        f32x4 xin = (acc0 + acc1) + (acc2 + acc3);

        // epilogue: g = sum_e coef[b,e]*acc_e + xg + bias
        // C/D layout: col = lane&15, row = 4*(lane>>4) + r   (verified m89)
        const int brow = (wv << 4) + (kg << 2);
#pragma unroll
        for (int r = 0; r < 4; ++r) {
            float4 cw = coefL[brow + r];
            g_lds[brow + r][rlo] = e0[r] * cw.x + e1[r] * cw.y + e2[r] * cw.z + e3[r] * cw.w
                                 + xin[r] + bias_l[brow + r][rlo];
        }
        __syncthreads();

        // ---- gate phase: thread (b_g, jj) ----
        float gi = g_lds[b_g][jj];
        float gf = g_lds[b_g][4 + jj];
        float gc = g_lds[b_g][8 + jj];
        float go = g_lds[b_g][12 + jj];
        float ig = 1.f / (1.f + __expf(-gi));
        float fg = 1.f / (1.f + __expf(-gf));
        float cc = tanhf(gc);
        float og = 1.f / (1.f + __expf(-go));
        float cn = fg * c_reg + ig * cc;
        float h  = og * tanhf(cn);
        c_reg = cn;

        // pack h into LDS, then 64x 8B sc1 stores (row b's 4 owned columns)
        ((unsigned short*)hpk)[tid] = f2bf(h);    // [b_g][jj] = tid
        __syncthreads();
        if (tid < 64)
            __hip_atomic_store((unsigned long long*)(hout + ((size_t)tid << 9) + j0),
                               hpk[tid], __ATOMIC_RELAXED, __HIP_MEMORY_SCOPE_AGENT);
        asm volatile("s_waitcnt vmcnt(0)" ::: "memory");
        if (tid == 0)
            __hip_atomic_store(&flags[wg], (unsigned)(t + 1), __ATOMIC_RELAXED,
                               __HIP_MEMORY_SCOPE_AGENT);

        // ---- post-arrive (overlaps other WGs' skew): out stores + next input GEMM
        out[((size_t)t << 15) + (b_g << 9) + j0 + jj] = h;
        if (t == T_STEPS - 1) {
            size_t base = (size_t)T_STEPS << 15;
            out[base + (b_g << 9) + j0 + jj] = h;
            out[base + (1 << 15) + (b_g << 9) + j0 + jj] = cn;
        }
        if (t + 1 < T_STEPS) {
            const bf16x8* xa = (const bf16x8*)A1 + ((size_t)(((t + 1) << 6) + arow) << 7) + kg;
            acc0 = (f32x4){0.f, 0.f, 0.f, 0.f}; acc1 = acc0; acc2 = acc0; acc3 = acc0;
#pragma unroll
            for (int kk = 0; kk < 32; ++kk) {
                bf16x8 a = xa[kk << 2];
                bf16x8 b = W1L[(kk << 6) + lane];
                f32x4& ac = (kk & 3) == 0 ? acc0 : (kk & 3) == 1 ? acc1 : (kk & 3) == 2 ? acc2 : acc3;
                ac = __builtin_amdgcn_mfma_f32_16x16x32_bf16(a, b, ac, 0, 0, 0);
            }
        }
    }
}

// ---------------- launch ----------------
extern "C" void kernel_launch(void* const* d_in, const int* in_sizes, int n_in,
                              void* d_out, int out_size, void* d_ws, size_t ws_size,
                              hipStream_t stream) {
    const float* x    = (const float*)d_in[0];
    const float* h0   = (const float*)d_in[1];
    const float* c0   = (const float*)d_in[2];
    const float* coef = (const float*)d_in[3];
    const float* Wi   = (const float*)d_in[4];
    const float* bi   = (const float*)d_in[5];
    const float* Wh   = (const float*)d_in[6];
    const float* bh   = (const float*)d_in[7];
    float* out = (float*)d_out;

    char* ws = (char*)d_ws;
    bf16*  W2T     = (bf16*)(ws);                                   // 8 MB
    bf16*  W1T     = (bf16*)(ws + (8u  << 20));                     // 4 MB
    bf16*  A1      = (bf16*)(ws + (12u << 20));                     // 16 MB
    float* biasmix = (float*)(ws + (28u << 20));                    // 512 KB
    bf16*  h_buf   = (bf16*)(ws + (28u << 20) + (512u << 10));      // 512 KB (8 slots x 64KB)
    unsigned* flags= (unsigned*)(ws + (29u << 20));                 // 512 B

    prep_w2t <<<16384, 256, 0, stream>>>(Wh, W2T);
    prep_w1t <<< 8192, 256, 0, stream>>>(Wi, W1T);
    prep_a1  <<<32768, 256, 0, stream>>>(x, coef, A1);
    prep_bias<<<  512, 256, 0, stream>>>(coef, bi, bh, biasmix);
    prep_h0  <<<  128, 256, 0, stream>>>(h0, h_buf, flags);

    void* args[] = {(void*)&W2T, (void*)&W1T, (void*)&A1, (void*)&biasmix,
                    (void*)&h_buf, (void*)&coef, (void*)&c0, (void*)&out, (void*)&flags};
    hipLaunchCooperativeKernel((void*)lstm_rec, dim3(128), dim3(256), args, 0, stream);
}

// Round 6
// 1090.616 us; speedup vs baseline: 5.2603x; 1.0179x over previous
//
#include <hip/hip_runtime.h>
#include <hip/hip_bf16.h>

typedef __hip_bfloat16 bf16;
typedef __attribute__((ext_vector_type(8))) short bf16x8;
typedef __attribute__((ext_vector_type(4))) float f32x4;

#define T_STEPS 128
#define NWG 128
#define ZSLOTS 8   // h-slot rotation depth; acquire-inv fires every ZSLOTS steps
// B=64, I=256, H=512, E=4, G=2048(=4H)
// Exchange buffer is h itself: h_buf[slot][b][j] bf16, 64KB/slot.
// Per-expert GEMM: acc_e[b,o] = sum_h h[b,h]*Wh[e,o,h]; epilogue applies
// g = sum_e coef[b,e]*acc_e + xg + bias.

__device__ inline unsigned short f2bf(float f) {
    bf16 b = __float2bfloat16(f);
    return *reinterpret_cast<unsigned short*>(&b);
}

// ---------------- prep kernels ----------------

// W2T[o][e*512+hh] = Wh[e][o][hh]   (bf16, [2048][2048])
__global__ void prep_w2t(const float* __restrict__ Wh, bf16* __restrict__ W2T) {
    int idx = blockIdx.x * 256 + threadIdx.x;          // 2048*2048
    int o = idx >> 11, k = idx & 2047;
    int e = k >> 9, hh = k & 511;
    W2T[idx] = __float2bfloat16(Wh[((size_t)((e << 11) + o) << 9) + hh]);
}

// W1T[o][e*256+i] = Wi[e][o][i]     (bf16, [2048][1024])
__global__ void prep_w1t(const float* __restrict__ Wi, bf16* __restrict__ W1T) {
    int idx = blockIdx.x * 256 + threadIdx.x;          // 2048*1024
    int o = idx >> 10, k = idx & 1023;
    int e = k >> 8, i = k & 255;
    W1T[idx] = __float2bfloat16(Wi[((size_t)((e << 11) + o) << 8) + i]);
}

// A1[t*64+b][e*256+i] = coef[b][e] * x[t][b][i]   (bf16, [8192][1024])
__global__ void prep_a1(const float* __restrict__ x, const float* __restrict__ coef,
                        bf16* __restrict__ A1) {
    int idx = blockIdx.x * 256 + threadIdx.x;          // 8192*1024
    int row = idx >> 10, k = idx & 1023;
    int b = row & 63;
    int e = k >> 8, i = k & 255;
    A1[idx] = __float2bfloat16(coef[(b << 2) + e] * x[((size_t)row << 8) + i]);
}

// biasmix[b][o] = sum_e coef[b][e]*(bi[e][o]+bh[e][o])   (f32, [64][2048])
__global__ void prep_bias(const float* __restrict__ coef, const float* __restrict__ bi,
                          const float* __restrict__ bh, float* __restrict__ biasmix) {
    int idx = blockIdx.x * 256 + threadIdx.x;          // 64*2048
    int b = idx >> 11, o = idx & 2047;
    float s = 0.f;
#pragma unroll
    for (int e = 0; e < 4; ++e)
        s += coef[(b << 2) + e] * (bi[(e << 11) + o] + bh[(e << 11) + o]);
    biasmix[idx] = s;
}

// h0 -> slot 0 (bf16 [64][512]); zero the 128 barrier flags
__global__ void prep_h0(const float* __restrict__ h0, bf16* __restrict__ hbuf,
                        unsigned* __restrict__ flags) {
    int idx = blockIdx.x * 256 + threadIdx.x;          // 64*512 = 32768
    if (idx < NWG) flags[idx] = 0u;
    hbuf[idx] = __float2bfloat16(h0[idx]);
}

// ---------------- main recurrent kernel ----------------
// 128 WGs x 256 threads (1 WG/CU). WG wg owns hidden units j0=4*wg..j0+3 (16
// gate columns o = q*512 + j0 + jj). Weights in LDS (linear fragment layout,
// conflict-free ds_read_b128); c-state in registers.
// Sync per step (R6): every WAVE independently wave-loads all 128 flags as
// uint2 (lane l -> flags[2l],[2l+1]) and proceeds with NO syncthreads on 7/8
// steps; inv-steps (t%8==0) rendezvous for a single buffer_inv. Release:
// LDS-pack h -> wave0 64x 8B sc1 stores -> vmcnt(0) -> flag store (validated).
// h fragments preloaded into 16 registers so all LLC loads are in flight at
// once (R5 interleaved load/mfma -> serialized ~600cy LLC loads).

__launch_bounds__(256, 1)
__global__ void lstm_rec(const bf16* __restrict__ W2T, const bf16* __restrict__ W1T,
                         const bf16* __restrict__ A1, const float* __restrict__ biasmix,
                         bf16* h_buf, const float* __restrict__ coef,
                         const float* __restrict__ c0, float* __restrict__ out,
                         unsigned* __restrict__ flags) {
    __shared__ bf16x8 W2L[4 * 16 * 64];   // [e][kk][lane] fragments, 64KB
    __shared__ bf16x8 W1L[32 * 64];       // [kk][lane] fragments, 32KB
    __shared__ float  g_lds [64][17];
    __shared__ float  bias_l[64][17];
    __shared__ float4 coefL[64];          // coef[b][0..3]
    __shared__ unsigned long long hpk[64]; // packed h row fragments (4x bf16)

    const int wg  = blockIdx.x;       // 0..127
    const int j0  = wg << 2;
    const int tid = threadIdx.x;
    const int lane = tid & 63;
    const int wv  = tid >> 6;         // wave 0..3 -> rows 16*wv..+15

    const int rlo  = lane & 15;       // MFMA col index (o within the 16)
    const int kg   = lane >> 4;       // k-group
    const int arow = (wv << 4) + rlo; // A-row (sample b) this lane loads

    // ---- build LDS weight fragments (once) ----
    for (int g = tid; g < 4096; g += 256) {
        int e = g >> 10, kk = (g >> 6) & 15, l = g & 63;
        int rl = l & 15, kgg = l >> 4;
        int o = ((rl >> 2) << 9) + j0 + (rl & 3);
        W2L[g] = *(const bf16x8*)(W2T + ((size_t)o << 11) + (e << 9) + (kk << 5) + (kgg << 3));
    }
    for (int g = tid; g < 2048; g += 256) {
        int kk = g >> 6, l = g & 63;
        int rl = l & 15, kgg = l >> 4;
        int o = ((rl >> 2) << 9) + j0 + (rl & 3);
        W1L[g] = *(const bf16x8*)(W1T + ((size_t)o << 10) + (kk << 5) + (kgg << 3));
    }
    for (int idx = tid; idx < 64 * 16; idx += 256) {
        int b = idx >> 4, n = idx & 15;
        int o = ((n >> 2) << 9) + j0 + (n & 3);
        bias_l[b][n] = biasmix[(b << 11) + o];
    }
    if (tid < 64) coefL[tid] = *(const float4*)(coef + (tid << 2));

    // ---- per-thread gate-phase state: tid -> (b_g, jj) ----
    const int b_g = tid >> 2, jj = tid & 3;
    float c_reg = c0[(b_g << 9) + j0 + jj];

    __syncthreads();

    f32x4 acc0, acc1, acc2, acc3;   // input-part accumulators (overlap slot)
    {
        const bf16x8* xa = (const bf16x8*)A1 + ((size_t)arow << 7) + kg;
        acc0 = (f32x4){0.f, 0.f, 0.f, 0.f}; acc1 = acc0; acc2 = acc0; acc3 = acc0;
#pragma unroll
        for (int kk = 0; kk < 32; ++kk) {
            bf16x8 a = xa[kk << 2];
            bf16x8 b = W1L[(kk << 6) + lane];
            f32x4& ac = (kk & 3) == 0 ? acc0 : (kk & 3) == 1 ? acc1 : (kk & 3) == 2 ? acc2 : acc3;
            ac = __builtin_amdgcn_mfma_f32_16x16x32_bf16(a, b, ac, 0, 0, 0);
        }
    }

    for (int t = 0; t < T_STEPS; ++t) {
        // ---- wait for epoch t: per-wave poll of ALL 128 flags (uint2/lane) ----
        if (t) {
            const unsigned long long* fp = (const unsigned long long*)flags + lane;
            const unsigned tt = (unsigned)t;
            while (true) {
                unsigned long long v = __hip_atomic_load(fp, __ATOMIC_RELAXED,
                                                         __HIP_MEMORY_SCOPE_AGENT);
                if ((unsigned)v >= tt && (unsigned)(v >> 32) >= tt) break;
                __builtin_amdgcn_s_sleep(1);
            }
            if ((t & (ZSLOTS - 1)) == 0) {
                // slow path every ZSLOTS steps: rendezvous + single L2 inv
                __syncthreads();
                if (tid < 64) __builtin_amdgcn_fence(__ATOMIC_ACQUIRE, "agent");
                __syncthreads();
            }
        }

        const bf16* hin  = h_buf + ((size_t)(t & (ZSLOTS - 1)) << 15);       // 64KB slots
        bf16*       hout = h_buf + ((size_t)((t + 1) & (ZSLOTS - 1)) << 15);

        // hidden part: preload all 16 A-fragments (loads fully in flight),
        // then per-expert MFMA (K=512 x 4 experts, shared A)
        f32x4 e0 = {0.f, 0.f, 0.f, 0.f}, e1 = e0, e2 = e0, e3 = e0;
        {
            const bf16x8* ha = (const bf16x8*)hin + (arow << 6) + kg;
            bf16x8 areg[16];
#pragma unroll
            for (int kk = 0; kk < 16; ++kk) areg[kk] = ha[kk << 2];
#pragma unroll
            for (int kk = 0; kk < 16; ++kk) {
                e0 = __builtin_amdgcn_mfma_f32_16x16x32_bf16(areg[kk], W2L[(kk << 6) + lane       ], e0, 0, 0, 0);
                e1 = __builtin_amdgcn_mfma_f32_16x16x32_bf16(areg[kk], W2L[(kk << 6) + lane + 1024], e1, 0, 0, 0);
                e2 = __builtin_amdgcn_mfma_f32_16x16x32_bf16(areg[kk], W2L[(kk << 6) + lane + 2048], e2, 0, 0, 0);
                e3 = __builtin_amdgcn_mfma_f32_16x16x32_bf16(areg[kk], W2L[(kk << 6) + lane + 3072], e3, 0, 0, 0);
            }
        }
        f32x4 xin = (acc0 + acc1) + (acc2 + acc3);

        // epilogue: g = sum_e coef[b,e]*acc_e + xg + bias
        // C/D layout: col = lane&15, row = 4*(lane>>4) + r   (verified m89)
        const int brow = (wv << 4) + (kg << 2);
#pragma unroll
        for (int r = 0; r < 4; ++r) {
            float4 cw = coefL[brow + r];
            g_lds[brow + r][rlo] = e0[r] * cw.x + e1[r] * cw.y + e2[r] * cw.z + e3[r] * cw.w
                                 + xin[r] + bias_l[brow + r][rlo];
        }
        __syncthreads();

        // ---- gate phase: thread (b_g, jj) ----
        float gi = g_lds[b_g][jj];
        float gf = g_lds[b_g][4 + jj];
        float gc = g_lds[b_g][8 + jj];
        float go = g_lds[b_g][12 + jj];
        float ig = 1.f / (1.f + __expf(-gi));
        float fg = 1.f / (1.f + __expf(-gf));
        float cc = tanhf(gc);
        float og = 1.f / (1.f + __expf(-go));
        float cn = fg * c_reg + ig * cc;
        float h  = og * tanhf(cn);
        c_reg = cn;

        // pack h into LDS, then wave0: 64x 8B sc1 stores (row b's 4 owned cols)
        ((unsigned short*)hpk)[tid] = f2bf(h);    // [b_g][jj] = tid
        __syncthreads();
        if (tid < 64)
            __hip_atomic_store((unsigned long long*)(hout + ((size_t)tid << 9) + j0),
                               hpk[tid], __ATOMIC_RELAXED, __HIP_MEMORY_SCOPE_AGENT);
        asm volatile("s_waitcnt vmcnt(0)" ::: "memory");
        if (tid == 0)
            __hip_atomic_store(&flags[wg], (unsigned)(t + 1), __ATOMIC_RELAXED,
                               __HIP_MEMORY_SCOPE_AGENT);

        // ---- post-arrive (off critical path): out stores + next input GEMM ----
        out[((size_t)t << 15) + (b_g << 9) + j0 + jj] = h;
        if (t == T_STEPS - 1) {
            size_t base = (size_t)T_STEPS << 15;
            out[base + (b_g << 9) + j0 + jj] = h;
            out[base + (1 << 15) + (b_g << 9) + j0 + jj] = cn;
        }
        if (t + 1 < T_STEPS) {
            const bf16x8* xa = (const bf16x8*)A1 + ((size_t)(((t + 1) << 6) + arow) << 7) + kg;
            acc0 = (f32x4){0.f, 0.f, 0.f, 0.f}; acc1 = acc0; acc2 = acc0; acc3 = acc0;
#pragma unroll
            for (int kk = 0; kk < 32; ++kk) {
                bf16x8 a = xa[kk << 2];
                bf16x8 b = W1L[(kk << 6) + lane];
                f32x4& ac = (kk & 3) == 0 ? acc0 : (kk & 3) == 1 ? acc1 : (kk & 3) == 2 ? acc2 : acc3;
                ac = __builtin_amdgcn_mfma_f32_16x16x32_bf16(a, b, ac, 0, 0, 0);
            }
        }
    }
}

// ---------------- launch ----------------
extern "C" void kernel_launch(void* const* d_in, const int* in_sizes, int n_in,
                              void* d_out, int out_size, void* d_ws, size_t ws_size,
                              hipStream_t stream) {
    const float* x    = (const float*)d_in[0];
    const float* h0   = (const float*)d_in[1];
    const float* c0   = (const float*)d_in[2];
    const float* coef = (const float*)d_in[3];
    const float* Wi   = (const float*)d_in[4];
    const float* bi   = (const float*)d_in[5];
    const float* Wh   = (const float*)d_in[6];
    const float* bh   = (const float*)d_in[7];
    float* out = (float*)d_out;

    char* ws = (char*)d_ws;
    bf16*  W2T     = (bf16*)(ws);                                   // 8 MB
    bf16*  W1T     = (bf16*)(ws + (8u  << 20));                     // 4 MB
    bf16*  A1      = (bf16*)(ws + (12u << 20));                     // 16 MB
    float* biasmix = (float*)(ws + (28u << 20));                    // 512 KB
    bf16*  h_buf   = (bf16*)(ws + (28u << 20) + (512u << 10));      // 512 KB (8 slots x 64KB)
    unsigned* flags= (unsigned*)(ws + (29u << 20));                 // 512 B

    prep_w2t <<<16384, 256, 0, stream>>>(Wh, W2T);
    prep_w1t <<< 8192, 256, 0, stream>>>(Wi, W1T);
    prep_a1  <<<32768, 256, 0, stream>>>(x, coef, A1);
    prep_bias<<<  512, 256, 0, stream>>>(coef, bi, bh, biasmix);
    prep_h0  <<<  128, 256, 0, stream>>>(h0, h_buf, flags);

    void* args[] = {(void*)&W2T, (void*)&W1T, (void*)&A1, (void*)&biasmix,
                    (void*)&h_buf, (void*)&coef, (void*)&c0, (void*)&out, (void*)&flags};
    hipLaunchCooperativeKernel((void*)lstm_rec, dim3(128), dim3(256), args, 0, stream);
}

// Round 10
// 1073.672 us; speedup vs baseline: 5.3433x; 1.0158x over previous
//
#include <hip/hip_runtime.h>
#include <hip/hip_bf16.h>

typedef __hip_bfloat16 bf16;
typedef __attribute__((ext_vector_type(8))) short bf16x8;
typedef __attribute__((ext_vector_type(4))) float f32x4;

#define T_STEPS 128
#define NWG 128
#define NFLAGS 512   // one flag per wave (128 WG x 4 waves)
#define ZSLOTS 8
// B=64, I=256, H=512, E=4, G=2048. 128 WGs x 256 thr (validated R6 geometry):
// WG wg owns 4 hidden units j0=4*wg..+3 (16 gate cols, n = q*4+jj). Weights in
// LDS (96KB linear fragments, validated). h exchange h_buf[slot][64][512],
// 8-slot rotated. R10 delta vs R6: gate exchange via 3 shfl_xor (no LDS, no
// syncthreads), h-pack via 2-shfl butterfly, per-WAVE release flags. Fast path
// has ZERO barriers; inv-rendezvous only every ZSLOTS steps.

__device__ inline unsigned short f2bf(float f) {
    bf16 b = __float2bfloat16(f);
    return *reinterpret_cast<unsigned short*>(&b);
}

// ---------------- prep kernels (verbatim R6) ----------------

// W2T[o][e*512+hh] = Wh[e][o][hh]   (bf16, [2048][2048])
__global__ void prep_w2t(const float* __restrict__ Wh, bf16* __restrict__ W2T) {
    int idx = blockIdx.x * 256 + threadIdx.x;          // 2048*2048
    int o = idx >> 11, k = idx & 2047;
    int e = k >> 9, hh = k & 511;
    W2T[idx] = __float2bfloat16(Wh[((size_t)((e << 11) + o) << 9) + hh]);
}

// W1T[o][e*256+i] = Wi[e][o][i]     (bf16, [2048][1024])
__global__ void prep_w1t(const float* __restrict__ Wi, bf16* __restrict__ W1T) {
    int idx = blockIdx.x * 256 + threadIdx.x;          // 2048*1024
    int o = idx >> 10, k = idx & 1023;
    int e = k >> 8, i = k & 255;
    W1T[idx] = __float2bfloat16(Wi[((size_t)((e << 11) + o) << 8) + i]);
}

// A1[t*64+b][e*256+i] = coef[b][e] * x[t][b][i]   (bf16, [8192][1024])
__global__ void prep_a1(const float* __restrict__ x, const float* __restrict__ coef,
                        bf16* __restrict__ A1) {
    int idx = blockIdx.x * 256 + threadIdx.x;          // 8192*1024
    int row = idx >> 10, k = idx & 1023;
    int b = row & 63;
    int e = k >> 8, i = k & 255;
    A1[idx] = __float2bfloat16(coef[(b << 2) + e] * x[((size_t)row << 8) + i]);
}

// biasmix[b][o] = sum_e coef[b][e]*(bi[e][o]+bh[e][o])   (f32, [64][2048])
__global__ void prep_bias(const float* __restrict__ coef, const float* __restrict__ bi,
                          const float* __restrict__ bh, float* __restrict__ biasmix) {
    int idx = blockIdx.x * 256 + threadIdx.x;          // 64*2048
    int b = idx >> 11, o = idx & 2047;
    float s = 0.f;
#pragma unroll
    for (int e = 0; e < 4; ++e)
        s += coef[(b << 2) + e] * (bi[(e << 11) + o] + bh[(e << 11) + o]);
    biasmix[idx] = s;
}

// h0 -> slot 0 (bf16 [64][512]); zero the 512 per-wave barrier flags
__global__ void prep_h0(const float* __restrict__ h0, bf16* __restrict__ hbuf,
                        unsigned* __restrict__ flags) {
    int idx = blockIdx.x * 256 + threadIdx.x;          // 64*512 = 32768
    if (idx < NFLAGS) flags[idx] = 0u;
    hbuf[idx] = __float2bfloat16(h0[idx]);
}

// ---------------- main recurrent kernel ----------------
__launch_bounds__(256, 1)
__global__ void lstm_rec(const bf16* __restrict__ W2T, const bf16* __restrict__ W1T,
                         const bf16* __restrict__ A1, const float* __restrict__ biasmix,
                         bf16* h_buf, const float* __restrict__ coef,
                         const float* __restrict__ c0, float* __restrict__ out,
                         unsigned* __restrict__ flags) {
    __shared__ bf16x8 W2L[4 * 16 * 64];   // [e][kk][lane] fragments, 64KB
    __shared__ bf16x8 W1L[32 * 64];       // [kk][lane] fragments, 32KB

    const int wg  = blockIdx.x;       // 0..127
    const int j0  = wg << 2;
    const int tid = threadIdx.x;
    const int lane = tid & 63;
    const int wv  = tid >> 6;         // wave 0..3 -> samples 16*wv..+15

    const int rlo  = lane & 15;       // MFMA col within 16: rlo = q*4 + jj
    const int kg   = lane >> 4;       // k-group / C row-quad
    const int arow = (wv << 4) + rlo; // A-row (sample) this lane loads
    const int q    = rlo >> 2;        // gate index of this lane's col
    const int jj   = rlo & 3;         // unit-within-WG
    const int samp = (wv << 4) + (kg << 2) + q;   // cell this lane owns
    const int o_ln = (q << 9) + j0 + jj;          // this lane's gate column

    // ---- build LDS weight fragments (verbatim R6) ----
    for (int g = tid; g < 4096; g += 256) {
        int e = g >> 10, kk = (g >> 6) & 15, l = g & 63;
        int rl = l & 15, kgg = l >> 4;
        int o = ((rl >> 2) << 9) + j0 + (rl & 3);
        W2L[g] = *(const bf16x8*)(W2T + ((size_t)o << 11) + (e << 9) + (kk << 5) + (kgg << 3));
    }
    for (int g = tid; g < 2048; g += 256) {
        int kk = g >> 6, l = g & 63;
        int rl = l & 15, kgg = l >> 4;
        int o = ((rl >> 2) << 9) + j0 + (rl & 3);
        W1L[g] = *(const bf16x8*)(W1T + ((size_t)o << 10) + (kk << 5) + (kgg << 3));
    }

    // ---- per-lane constants in registers (R6 kept these in LDS) ----
    float bias_r[4];
    float4 cw[4];
#pragma unroll
    for (int r = 0; r < 4; ++r) {
        int row = (wv << 4) + (kg << 2) + r;
        bias_r[r] = biasmix[((size_t)row << 11) + o_ln];
        cw[r] = *(const float4*)(coef + (row << 2));
    }
    float c_reg = c0[((size_t)samp << 9) + j0 + jj];

    __syncthreads();

    f32x4 acc0, acc1, acc2, acc3;   // input-part accumulators (overlap slot)
    {
        const bf16x8* xa = (const bf16x8*)A1 + ((size_t)arow << 7) + kg;
        acc0 = (f32x4){0.f, 0.f, 0.f, 0.f}; acc1 = acc0; acc2 = acc0; acc3 = acc0;
#pragma unroll
        for (int kk = 0; kk < 32; ++kk) {
            bf16x8 a = xa[kk << 2];
            bf16x8 b = W1L[(kk << 6) + lane];
            f32x4& ac = (kk & 3) == 0 ? acc0 : (kk & 3) == 1 ? acc1 : (kk & 3) == 2 ? acc2 : acc3;
            ac = __builtin_amdgcn_mfma_f32_16x16x32_bf16(a, b, ac, 0, 0, 0);
        }
    }

    for (int t = 0; t < T_STEPS; ++t) {
        // ---- wait for epoch t: per-wave poll of all 512 flags (4 u64/lane) ----
        if (t) {
            const unsigned long long* f64 = (const unsigned long long*)flags + (lane << 2);
            const unsigned tt = (unsigned)t;
            while (true) {
                unsigned long long v0 = __hip_atomic_load(f64 + 0, __ATOMIC_RELAXED, __HIP_MEMORY_SCOPE_AGENT);
                unsigned long long v1 = __hip_atomic_load(f64 + 1, __ATOMIC_RELAXED, __HIP_MEMORY_SCOPE_AGENT);
                unsigned long long v2 = __hip_atomic_load(f64 + 2, __ATOMIC_RELAXED, __HIP_MEMORY_SCOPE_AGENT);
                unsigned long long v3 = __hip_atomic_load(f64 + 3, __ATOMIC_RELAXED, __HIP_MEMORY_SCOPE_AGENT);
                if ((unsigned)v0 >= tt && (unsigned)(v0 >> 32) >= tt &&
                    (unsigned)v1 >= tt && (unsigned)(v1 >> 32) >= tt &&
                    (unsigned)v2 >= tt && (unsigned)(v2 >> 32) >= tt &&
                    (unsigned)v3 >= tt && (unsigned)(v3 >> 32) >= tt) break;
                __builtin_amdgcn_s_sleep(1);
            }
            if ((t & (ZSLOTS - 1)) == 0) {   // slow path: rendezvous + L2 inv (no wbl2)
                __syncthreads();
                if (tid < 64) __builtin_amdgcn_fence(__ATOMIC_ACQUIRE, "agent");
                __syncthreads();
            }
        }

        const bf16* hin  = h_buf + ((size_t)(t & (ZSLOTS - 1)) << 15);       // 64KB slots
        bf16*       hout = h_buf + ((size_t)((t + 1) & (ZSLOTS - 1)) << 15);

        // ---- hidden GEMM (verbatim R6): preload 16 A-frags, 4 experts ----
        f32x4 e0 = {0.f, 0.f, 0.f, 0.f}, e1 = e0, e2 = e0, e3 = e0;
        {
            const bf16x8* ha = (const bf16x8*)hin + (arow << 6) + kg;
            bf16x8 areg[16];
#pragma unroll
            for (int kk = 0; kk < 16; ++kk) areg[kk] = ha[kk << 2];
#pragma unroll
            for (int kk = 0; kk < 16; ++kk) {
                e0 = __builtin_amdgcn_mfma_f32_16x16x32_bf16(areg[kk], W2L[(kk << 6) + lane       ], e0, 0, 0, 0);
                e1 = __builtin_amdgcn_mfma_f32_16x16x32_bf16(areg[kk], W2L[(kk << 6) + lane + 1024], e1, 0, 0, 0);
                e2 = __builtin_amdgcn_mfma_f32_16x16x32_bf16(areg[kk], W2L[(kk << 6) + lane + 2048], e2, 0, 0, 0);
                e3 = __builtin_amdgcn_mfma_f32_16x16x32_bf16(areg[kk], W2L[(kk << 6) + lane + 3072], e3, 0, 0, 0);
            }
        }

        // ---- epilogue in registers: g = sum_e coef*acc_e + xg + bias ----
        // C/D layout: col = lane&15, row = 4*(lane>>4)+r (verified m89); rows
        // here are samples (wv<<4)+(kg<<2)+r.
        f32x4 gv;
        {
            f32x4 xin = (acc0 + acc1) + (acc2 + acc3);
#pragma unroll
            for (int r = 0; r < 4; ++r)
                gv[r] = e0[r] * cw[r].x + e1[r] * cw[r].y + e2[r] * cw[r].z + e3[r] * cw[r].w
                      + xin[r] + bias_r[r];
        }

        // ---- gate exchange among 4 gate-lanes (xor 4/8/12 flip q bits) ----
        // lane q holds gate q for rows +0..3; after exchange it has all 4
        // gates of row +q (its cell samp).
        const bool b0 = (q & 1), b1 = (q & 2);
        float own = b1 ? (b0 ? gv[3] : gv[2]) : (b0 ? gv[1] : gv[0]);   // g[q]
        float s1  = b1 ? (b0 ? gv[2] : gv[3]) : (b0 ? gv[0] : gv[1]);   // g[q^1]
        float s2  = b1 ? (b0 ? gv[1] : gv[0]) : (b0 ? gv[3] : gv[2]);   // g[q^2]
        float s3  = b1 ? (b0 ? gv[0] : gv[1]) : (b0 ? gv[2] : gv[3]);   // g[q^3]
        float r1 = __shfl_xor(s1, 4);    // gate q^1 of my row
        float r2 = __shfl_xor(s2, 8);    // gate q^2
        float r3 = __shfl_xor(s3, 12);   // gate q^3
        float iG = (q == 0) ? own : (q == 1) ? r1 : (q == 2) ? r2 : r3;
        float fG = (q == 0) ? r1 : (q == 1) ? own : (q == 2) ? r3 : r2;
        float cG = (q == 0) ? r2 : (q == 1) ? r3 : (q == 2) ? own : r1;
        float oG = (q == 0) ? r3 : (q == 1) ? r2 : (q == 2) ? r1 : own;

        // ---- cell update (1 cell per lane) ----
        float ig = 1.f / (1.f + __expf(-iG));
        float fg = 1.f / (1.f + __expf(-fG));
        float cc = tanhf(cG);
        float og = 1.f / (1.f + __expf(-oG));
        float cn = fg * c_reg + ig * cc;
        float hv = og * tanhf(cn);
        c_reg = cn;

        // ---- pack the 4 units of my sample row via butterfly over jj ----
        unsigned u = (unsigned)f2bf(hv);
        unsigned w = (unsigned)__shfl_xor((int)u, 1);
        unsigned pair = (jj & 1) ? (w | (u << 16)) : (u | (w << 16));
        unsigned p2 = (unsigned)__shfl_xor((int)pair, 2);
        unsigned long long v64 = (jj & 2)
            ? ((unsigned long long)p2 | ((unsigned long long)pair << 32))
            : ((unsigned long long)pair | ((unsigned long long)p2 << 32));
        if (jj == 0)
            __hip_atomic_store((unsigned long long*)(hout + ((size_t)samp << 9) + j0),
                               v64, __ATOMIC_RELAXED, __HIP_MEMORY_SCOPE_AGENT);

        // ---- release: per-wave drain + per-wave flag (no barriers) ----
        asm volatile("s_waitcnt vmcnt(0)" ::: "memory");
        if (lane == 0)
            __hip_atomic_store(&flags[(wg << 2) + wv], (unsigned)(t + 1),
                               __ATOMIC_RELAXED, __HIP_MEMORY_SCOPE_AGENT);

        // ---- post-arrive (off critical path): out stores + next input GEMM ----
        out[((size_t)t << 15) + ((size_t)samp << 9) + j0 + jj] = hv;
        if (t == T_STEPS - 1) {
            size_t base = (size_t)T_STEPS << 15;
            out[base + ((size_t)samp << 9) + j0 + jj] = hv;
            out[base + (1 << 15) + ((size_t)samp << 9) + j0 + jj] = cn;
        }
        if (t + 1 < T_STEPS) {
            const bf16x8* xa = (const bf16x8*)A1 + ((size_t)(((t + 1) << 6) + arow) << 7) + kg;
            acc0 = (f32x4){0.f, 0.f, 0.f, 0.f}; acc1 = acc0; acc2 = acc0; acc3 = acc0;
#pragma unroll
            for (int kk = 0; kk < 32; ++kk) {
                bf16x8 a = xa[kk << 2];
                bf16x8 b = W1L[(kk << 6) + lane];
                f32x4& ac = (kk & 3) == 0 ? acc0 : (kk & 3) == 1 ? acc1 : (kk & 3) == 2 ? acc2 : acc3;
                ac = __builtin_amdgcn_mfma_f32_16x16x32_bf16(a, b, ac, 0, 0, 0);
            }
        }
    }
}

// ---------------- launch (ws layout verbatim R6; flags grown to 2KB) ----------------
extern "C" void kernel_launch(void* const* d_in, const int* in_sizes, int n_in,
                              void* d_out, int out_size, void* d_ws, size_t ws_size,
                              hipStream_t stream) {
    const float* x    = (const float*)d_in[0];
    const float* h0   = (const float*)d_in[1];
    const float* c0   = (const float*)d_in[2];
    const float* coef = (const float*)d_in[3];
    const float* Wi   = (const float*)d_in[4];
    const float* bi   = (const float*)d_in[5];
    const float* Wh   = (const float*)d_in[6];
    const float* bh   = (const float*)d_in[7];
    float* out = (float*)d_out;

    char* ws = (char*)d_ws;
    bf16*   W2T     = (bf16*)(ws);                                   // 8 MB
    bf16*   W1T     = (bf16*)(ws + (8u  << 20));                     // 4 MB
    bf16*   A1      = (bf16*)(ws + (12u << 20));                     // 16 MB
    float*  biasmix = (float*)(ws + (28u << 20));                    // 512 KB
    bf16*   h_buf   = (bf16*)(ws + (28u << 20) + (512u << 10));      // 512 KB (8x64KB)
    unsigned* flags = (unsigned*)(ws + (29u << 20));                 // 2 KB

    prep_w2t <<<16384, 256, 0, stream>>>(Wh, W2T);
    prep_w1t <<< 8192, 256, 0, stream>>>(Wi, W1T);
    prep_a1  <<<32768, 256, 0, stream>>>(x, coef, A1);
    prep_bias<<<  512, 256, 0, stream>>>(coef, bi, bh, biasmix);
    prep_h0  <<<  128, 256, 0, stream>>>(h0, h_buf, flags);

    void* args[] = {(void*)&W2T, (void*)&W1T, (void*)&A1, (void*)&biasmix,
                    (void*)&h_buf, (void*)&coef, (void*)&c0, (void*)&out, (void*)&flags};
    hipLaunchCooperativeKernel((void*)lstm_rec, dim3(NWG), dim3(256), args, 0, stream);
}

// Round 11
// 1039.898 us; speedup vs baseline: 5.5168x; 1.0325x over previous
//
#include <hip/hip_runtime.h>
#include <hip/hip_bf16.h>

typedef __hip_bfloat16 bf16;
typedef __attribute__((ext_vector_type(8))) short bf16x8;
typedef __attribute__((ext_vector_type(4))) short bf16x4;
typedef __attribute__((ext_vector_type(4))) float f32x4;

#define T_STEPS 128
#define NWG 128
#define NFLAGS 512   // one flag per wave (128 WG x 4 waves)
#define ZSLOTS 8
// B=64, I=256, H=512, E=4, G=2048. 128 WGs x 256 thr (R10 verified geometry):
// WG wg owns 4 hidden units j0=4*wg..+3 (16 gate cols, n = q*4+jj). Weights in
// LDS (96KB linear fragments). R11 delta vs R10: h exchange buffer TRANSPOSED
// to hq[slot][ug][samp] (ug=unit/4=wg, 8B entries) so each wave's release is
// ONE contiguous 128B line store (R10: 16 scattered 8B partial-line RMWs/wave,
// 8192/step at the LLC). Consumer loads become bf16x4 pairs. Sync skeleton
// (sc1 stores + vmcnt + per-wave flags, sleep-poll, inv every ZSLOTS) verbatim.

__device__ inline unsigned short f2bf(float f) {
    bf16 b = __float2bfloat16(f);
    return *reinterpret_cast<unsigned short*>(&b);
}

// ---------------- prep kernels ----------------

// W2T[o][e*512+hh] = Wh[e][o][hh]   (bf16, [2048][2048])
__global__ void prep_w2t(const float* __restrict__ Wh, bf16* __restrict__ W2T) {
    int idx = blockIdx.x * 256 + threadIdx.x;          // 2048*2048
    int o = idx >> 11, k = idx & 2047;
    int e = k >> 9, hh = k & 511;
    W2T[idx] = __float2bfloat16(Wh[((size_t)((e << 11) + o) << 9) + hh]);
}

// W1T[o][e*256+i] = Wi[e][o][i]     (bf16, [2048][1024])
__global__ void prep_w1t(const float* __restrict__ Wi, bf16* __restrict__ W1T) {
    int idx = blockIdx.x * 256 + threadIdx.x;          // 2048*1024
    int o = idx >> 10, k = idx & 1023;
    int e = k >> 8, i = k & 255;
    W1T[idx] = __float2bfloat16(Wi[((size_t)((e << 11) + o) << 8) + i]);
}

// A1[t*64+b][e*256+i] = coef[b][e] * x[t][b][i]   (bf16, [8192][1024])
__global__ void prep_a1(const float* __restrict__ x, const float* __restrict__ coef,
                        bf16* __restrict__ A1) {
    int idx = blockIdx.x * 256 + threadIdx.x;          // 8192*1024
    int row = idx >> 10, k = idx & 1023;
    int b = row & 63;
    int e = k >> 8, i = k & 255;
    A1[idx] = __float2bfloat16(coef[(b << 2) + e] * x[((size_t)row << 8) + i]);
}

// biasmix[b][o] = sum_e coef[b][e]*(bi[e][o]+bh[e][o])   (f32, [64][2048])
__global__ void prep_bias(const float* __restrict__ coef, const float* __restrict__ bi,
                          const float* __restrict__ bh, float* __restrict__ biasmix) {
    int idx = blockIdx.x * 256 + threadIdx.x;          // 64*2048
    int b = idx >> 11, o = idx & 2047;
    float s = 0.f;
#pragma unroll
    for (int e = 0; e < 4; ++e)
        s += coef[(b << 2) + e] * (bi[(e << 11) + o] + bh[(e << 11) + o]);
    biasmix[idx] = s;
}

// h0 -> slot 0 in TRANSPOSED layout hq[ug][samp][uu]; zero the 512 flags
__global__ void prep_h0(const float* __restrict__ h0, bf16* __restrict__ hbuf,
                        unsigned* __restrict__ flags) {
    int idx = blockIdx.x * 256 + threadIdx.x;          // 32768
    if (idx < NFLAGS) flags[idx] = 0u;
    int ug = idx >> 8, rem = idx & 255;
    int samp = rem >> 2, uu = rem & 3;
    hbuf[idx] = __float2bfloat16(h0[((size_t)samp << 9) + (ug << 2) + uu]);
}

// ---------------- main recurrent kernel ----------------
__launch_bounds__(256, 1)
__global__ void lstm_rec(const bf16* __restrict__ W2T, const bf16* __restrict__ W1T,
                         const bf16* __restrict__ A1, const float* __restrict__ biasmix,
                         bf16* h_buf, const float* __restrict__ coef,
                         const float* __restrict__ c0, float* __restrict__ out,
                         unsigned* __restrict__ flags) {
    __shared__ bf16x8 W2L[4 * 16 * 64];   // [e][kk][lane] fragments, 64KB
    __shared__ bf16x8 W1L[32 * 64];       // [kk][lane] fragments, 32KB

    const int wg  = blockIdx.x;       // 0..127
    const int j0  = wg << 2;
    const int tid = threadIdx.x;
    const int lane = tid & 63;
    const int wv  = tid >> 6;         // wave 0..3 -> samples 16*wv..+15

    const int rlo  = lane & 15;       // MFMA col within 16: rlo = q*4 + jj
    const int kg   = lane >> 4;       // k-group / C row-quad
    const int arow = (wv << 4) + rlo; // A-row (sample) this lane loads
    const int q    = rlo >> 2;        // gate index of this lane's col
    const int jj   = rlo & 3;         // unit-within-WG
    const int samp = (wv << 4) + (kg << 2) + q;   // cell this lane owns
    const int o_ln = (q << 9) + j0 + jj;          // this lane's gate column

    // ---- build LDS weight fragments (verbatim R6/R10) ----
    for (int g = tid; g < 4096; g += 256) {
        int e = g >> 10, kk = (g >> 6) & 15, l = g & 63;
        int rl = l & 15, kgg = l >> 4;
        int o = ((rl >> 2) << 9) + j0 + (rl & 3);
        W2L[g] = *(const bf16x8*)(W2T + ((size_t)o << 11) + (e << 9) + (kk << 5) + (kgg << 3));
    }
    for (int g = tid; g < 2048; g += 256) {
        int kk = g >> 6, l = g & 63;
        int rl = l & 15, kgg = l >> 4;
        int o = ((rl >> 2) << 9) + j0 + (rl & 3);
        W1L[g] = *(const bf16x8*)(W1T + ((size_t)o << 10) + (kk << 5) + (kgg << 3));
    }

    // ---- per-lane constants in registers ----
    float bias_r[4];
    float4 cw[4];
#pragma unroll
    for (int r = 0; r < 4; ++r) {
        int row = (wv << 4) + (kg << 2) + r;
        bias_r[r] = biasmix[((size_t)row << 11) + o_ln];
        cw[r] = *(const float4*)(coef + (row << 2));
    }
    float c_reg = c0[((size_t)samp << 9) + j0 + jj];

    __syncthreads();

    f32x4 acc0, acc1, acc2, acc3;   // input-part accumulators (overlap slot)
    {
        const bf16x8* xa = (const bf16x8*)A1 + ((size_t)arow << 7) + kg;
        acc0 = (f32x4){0.f, 0.f, 0.f, 0.f}; acc1 = acc0; acc2 = acc0; acc3 = acc0;
#pragma unroll
        for (int kk = 0; kk < 32; ++kk) {
            bf16x8 a = xa[kk << 2];
            bf16x8 b = W1L[(kk << 6) + lane];
            f32x4& ac = (kk & 3) == 0 ? acc0 : (kk & 3) == 1 ? acc1 : (kk & 3) == 2 ? acc2 : acc3;
            ac = __builtin_amdgcn_mfma_f32_16x16x32_bf16(a, b, ac, 0, 0, 0);
        }
    }

    for (int t = 0; t < T_STEPS; ++t) {
        // ---- wait for epoch t: per-wave poll of all 512 flags (4 u64/lane) ----
        if (t) {
            const unsigned long long* f64 = (const unsigned long long*)flags + (lane << 2);
            const unsigned tt = (unsigned)t;
            while (true) {
                unsigned long long v0 = __hip_atomic_load(f64 + 0, __ATOMIC_RELAXED, __HIP_MEMORY_SCOPE_AGENT);
                unsigned long long v1 = __hip_atomic_load(f64 + 1, __ATOMIC_RELAXED, __HIP_MEMORY_SCOPE_AGENT);
                unsigned long long v2 = __hip_atomic_load(f64 + 2, __ATOMIC_RELAXED, __HIP_MEMORY_SCOPE_AGENT);
                unsigned long long v3 = __hip_atomic_load(f64 + 3, __ATOMIC_RELAXED, __HIP_MEMORY_SCOPE_AGENT);
                if ((unsigned)v0 >= tt && (unsigned)(v0 >> 32) >= tt &&
                    (unsigned)v1 >= tt && (unsigned)(v1 >> 32) >= tt &&
                    (unsigned)v2 >= tt && (unsigned)(v2 >> 32) >= tt &&
                    (unsigned)v3 >= tt && (unsigned)(v3 >> 32) >= tt) break;
                __builtin_amdgcn_s_sleep(2);
            }
            if ((t & (ZSLOTS - 1)) == 0) {   // slow path: rendezvous + L2 inv (no wbl2)
                __syncthreads();
                if (tid < 64) __builtin_amdgcn_fence(__ATOMIC_ACQUIRE, "agent");
                __syncthreads();
            }
        }

        // h slots in TRANSPOSED layout: hq[ug][samp], 8B entries, 64KB/slot
        const bf16* hin  = h_buf + ((size_t)(t & (ZSLOTS - 1)) << 15);
        bf16*       hout = h_buf + ((size_t)((t + 1) & (ZSLOTS - 1)) << 15);

        // ---- hidden GEMM: preload 16 A-frags (two 8B loads each), 4 experts ----
        f32x4 e0 = {0.f, 0.f, 0.f, 0.f}, e1 = e0, e2 = e0, e3 = e0;
        {
            const bf16x4* hb = (const bf16x4*)hin;
            bf16x8 areg[16];
#pragma unroll
            for (int kk = 0; kk < 16; ++kk) {
                int ug = (kk << 3) + (kg << 1);
                bf16x4 lo = hb[(ug << 6) + arow];
                bf16x4 hi = hb[((ug + 1) << 6) + arow];
                areg[kk] = __builtin_shufflevector(lo, hi, 0, 1, 2, 3, 4, 5, 6, 7);
            }
#pragma unroll
            for (int kk = 0; kk < 16; ++kk) {
                e0 = __builtin_amdgcn_mfma_f32_16x16x32_bf16(areg[kk], W2L[(kk << 6) + lane       ], e0, 0, 0, 0);
                e1 = __builtin_amdgcn_mfma_f32_16x16x32_bf16(areg[kk], W2L[(kk << 6) + lane + 1024], e1, 0, 0, 0);
                e2 = __builtin_amdgcn_mfma_f32_16x16x32_bf16(areg[kk], W2L[(kk << 6) + lane + 2048], e2, 0, 0, 0);
                e3 = __builtin_amdgcn_mfma_f32_16x16x32_bf16(areg[kk], W2L[(kk << 6) + lane + 3072], e3, 0, 0, 0);
            }
        }

        // ---- epilogue in registers: g = sum_e coef*acc_e + xg + bias ----
        f32x4 gv;
        {
            f32x4 xin = (acc0 + acc1) + (acc2 + acc3);
#pragma unroll
            for (int r = 0; r < 4; ++r)
                gv[r] = e0[r] * cw[r].x + e1[r] * cw[r].y + e2[r] * cw[r].z + e3[r] * cw[r].w
                      + xin[r] + bias_r[r];
        }

        // ---- gate exchange among 4 gate-lanes (xor 4/8/12) — verified R10 ----
        const bool b0 = (q & 1), b1 = (q & 2);
        float own = b1 ? (b0 ? gv[3] : gv[2]) : (b0 ? gv[1] : gv[0]);   // g[q]
        float s1  = b1 ? (b0 ? gv[2] : gv[3]) : (b0 ? gv[0] : gv[1]);   // g[q^1]
        float s2  = b1 ? (b0 ? gv[1] : gv[0]) : (b0 ? gv[3] : gv[2]);   // g[q^2]
        float s3  = b1 ? (b0 ? gv[0] : gv[1]) : (b0 ? gv[2] : gv[3]);   // g[q^3]
        float r1 = __shfl_xor(s1, 4);
        float r2 = __shfl_xor(s2, 8);
        float r3 = __shfl_xor(s3, 12);
        float iG = (q == 0) ? own : (q == 1) ? r1 : (q == 2) ? r2 : r3;
        float fG = (q == 0) ? r1 : (q == 1) ? own : (q == 2) ? r3 : r2;
        float cG = (q == 0) ? r2 : (q == 1) ? r3 : (q == 2) ? own : r1;
        float oG = (q == 0) ? r3 : (q == 1) ? r2 : (q == 2) ? r1 : own;

        // ---- cell update (1 cell per lane) ----
        float ig = 1.f / (1.f + __expf(-iG));
        float fg = 1.f / (1.f + __expf(-fG));
        float cc = tanhf(cG);
        float og = 1.f / (1.f + __expf(-oG));
        float cn = fg * c_reg + ig * cc;
        float hv = og * tanhf(cn);
        c_reg = cn;

        // ---- pack 4 units of my sample via butterfly over jj (verified R10) ----
        unsigned u = (unsigned)f2bf(hv);
        unsigned w = (unsigned)__shfl_xor((int)u, 1);
        unsigned pair = (jj & 1) ? (w | (u << 16)) : (u | (w << 16));
        unsigned p2 = (unsigned)__shfl_xor((int)pair, 2);
        unsigned long long v64 = (jj & 2)
            ? ((unsigned long long)p2 | ((unsigned long long)pair << 32))
            : ((unsigned long long)pair | ((unsigned long long)p2 << 32));
        // TRANSPOSED store: entry [ug=wg][samp] -> wave's 16 stores = one
        // contiguous aligned 128B line at hout + wg*512B + wv*128B
        if (jj == 0)
            __hip_atomic_store((unsigned long long*)hout + (wg << 6) + samp,
                               v64, __ATOMIC_RELAXED, __HIP_MEMORY_SCOPE_AGENT);

        // ---- release: per-wave drain (1 line) + per-wave flag ----
        asm volatile("s_waitcnt vmcnt(0)" ::: "memory");
        if (lane == 0)
            __hip_atomic_store(&flags[(wg << 2) + wv], (unsigned)(t + 1),
                               __ATOMIC_RELAXED, __HIP_MEMORY_SCOPE_AGENT);

        // ---- post-arrive (off critical path): out stores + next input GEMM ----
        out[((size_t)t << 15) + ((size_t)samp << 9) + j0 + jj] = hv;
        if (t == T_STEPS - 1) {
            size_t base = (size_t)T_STEPS << 15;
            out[base + ((size_t)samp << 9) + j0 + jj] = hv;
            out[base + (1 << 15) + ((size_t)samp << 9) + j0 + jj] = cn;
        }
        if (t + 1 < T_STEPS) {
            const bf16x8* xa = (const bf16x8*)A1 + ((size_t)(((t + 1) << 6) + arow) << 7) + kg;
            acc0 = (f32x4){0.f, 0.f, 0.f, 0.f}; acc1 = acc0; acc2 = acc0; acc3 = acc0;
#pragma unroll
            for (int kk = 0; kk < 32; ++kk) {
                bf16x8 a = xa[kk << 2];
                bf16x8 b = W1L[(kk << 6) + lane];
                f32x4& ac = (kk & 3) == 0 ? acc0 : (kk & 3) == 1 ? acc1 : (kk & 3) == 2 ? acc2 : acc3;
                ac = __builtin_amdgcn_mfma_f32_16x16x32_bf16(a, b, ac, 0, 0, 0);
            }
        }
    }
}

// ---------------- launch (ws layout verbatim R10) ----------------
extern "C" void kernel_launch(void* const* d_in, const int* in_sizes, int n_in,
                              void* d_out, int out_size, void* d_ws, size_t ws_size,
                              hipStream_t stream) {
    const float* x    = (const float*)d_in[0];
    const float* h0   = (const float*)d_in[1];
    const float* c0   = (const float*)d_in[2];
    const float* coef = (const float*)d_in[3];
    const float* Wi   = (const float*)d_in[4];
    const float* bi   = (const float*)d_in[5];
    const float* Wh   = (const float*)d_in[6];
    const float* bh   = (const float*)d_in[7];
    float* out = (float*)d_out;

    char* ws = (char*)d_ws;
    bf16*   W2T     = (bf16*)(ws);                                   // 8 MB
    bf16*   W1T     = (bf16*)(ws + (8u  << 20));                     // 4 MB
    bf16*   A1      = (bf16*)(ws + (12u << 20));                     // 16 MB
    float*  biasmix = (float*)(ws + (28u << 20));                    // 512 KB
    bf16*   h_buf   = (bf16*)(ws + (28u << 20) + (512u << 10));      // 512 KB (8x64KB)
    unsigned* flags = (unsigned*)(ws + (29u << 20));                 // 2 KB

    prep_w2t <<<16384, 256, 0, stream>>>(Wh, W2T);
    prep_w1t <<< 8192, 256, 0, stream>>>(Wi, W1T);
    prep_a1  <<<32768, 256, 0, stream>>>(x, coef, A1);
    prep_bias<<<  512, 256, 0, stream>>>(coef, bi, bh, biasmix);
    prep_h0  <<<  128, 256, 0, stream>>>(h0, h_buf, flags);

    void* args[] = {(void*)&W2T, (void*)&W1T, (void*)&A1, (void*)&biasmix,
                    (void*)&h_buf, (void*)&coef, (void*)&c0, (void*)&out, (void*)&flags};
    hipLaunchCooperativeKernel((void*)lstm_rec, dim3(NWG), dim3(256), args, 0, stream);
}